// Round 15
// baseline (491.665 us; speedup 1.0000x reference)
//
#include <hip/hip_runtime.h>
#include <hip/hip_bf16.h>

#define NEG_SLOPE 0.2f
#define BSHIFT 9                 // 512 nodes per bucket
#define MAXBUCK 128              // covers N up to 65536

static __device__ __forceinline__ float b2f(unsigned short u){
  return __uint_as_float(((unsigned int)u) << 16);
}
static __device__ __forceinline__ unsigned int pack_bf2(float a, float b){
  unsigned int ua = __float_as_uint(a);
  unsigned int ub = __float_as_uint(b);
  unsigned int ra = (ua + 0x7fffu + ((ua >> 16) & 1u)) >> 16;   // RNE
  unsigned int rb = (ub + 0x7fffu + ((ub >> 16) & 1u)) >> 16;
  return ra | (rb << 16);
}

// ---------------- workspace init ----------------
__global__ __launch_bounds__(256) void k_init(int* deg, int* gs, int* ge,
    float* pool, int n1, int G){
  int i = blockIdx.x * 256 + threadIdx.x;
  if(i < n1) deg[i] = 0;
  if(i < G){ gs[i] = 0x7fffffff; ge[i] = 0; }
  if(i < G * 128) pool[i] = 0.f;
}

// ---------------- GEMM: f32 out (+optional bias). Round-11 inner loop: ~100 VGPR, no spill.
// NOTE: 4-k float4-A blocking (round 12) spilled to scratch (256 VGPR, 2 GB traffic) — do not reintroduce.
__global__ __launch_bounds__(256) void k_gemm(const float* __restrict__ A,
    const float* __restrict__ W, const float* __restrict__ bias,
    float* __restrict__ out, int nrows){
  __shared__ float Wl[64 * 128];
  __shared__ float Al[32 * 128];
  const int t = threadIdx.x;
  const int row0 = blockIdx.x * 32;
  #pragma unroll
  for(int i = 0; i < 8; i++){
    int idx = t + i * 256;
    int r = idx >> 6, kk = idx & 63;
    int rg = row0 + r; if(rg >= nrows) rg = nrows - 1;
    ((float2*)Al)[r * 64 + kk] = ((const float2*)A)[(size_t)rg * 64 + kk];
  }
  const int c0 = (t & 31) * 4;
  const int rb = (t >> 5) * 4;
  float acc[4][4] = {};
  const float4* W4 = (const float4*)W;
  #pragma unroll
  for(int h = 0; h < 2; h++){
    if(h) __syncthreads();
    #pragma unroll
    for(int i = 0; i < 8; i++) ((float4*)Wl)[t + i * 256] = W4[h * 2048 + t + i * 256];
    __syncthreads();
    const int kb = h * 64;
    #pragma unroll 8
    for(int k = 0; k < 64; k++){
      float4 wv = *(const float4*)&Wl[k * 128 + c0];
      float a0 = Al[(rb+0)*128 + kb + k];
      float a1 = Al[(rb+1)*128 + kb + k];
      float a2 = Al[(rb+2)*128 + kb + k];
      float a3 = Al[(rb+3)*128 + kb + k];
      acc[0][0] += a0*wv.x; acc[0][1] += a0*wv.y; acc[0][2] += a0*wv.z; acc[0][3] += a0*wv.w;
      acc[1][0] += a1*wv.x; acc[1][1] += a1*wv.y; acc[1][2] += a1*wv.z; acc[1][3] += a1*wv.w;
      acc[2][0] += a2*wv.x; acc[2][1] += a2*wv.y; acc[2][2] += a2*wv.z; acc[2][3] += a2*wv.w;
      acc[3][0] += a3*wv.x; acc[3][1] += a3*wv.y; acc[3][2] += a3*wv.z; acc[3][3] += a3*wv.w;
    }
  }
  float b0 = 0.f, b1 = 0.f, b2v = 0.f, b3 = 0.f;
  if(bias){ b0 = bias[c0]; b1 = bias[c0+1]; b2v = bias[c0+2]; b3 = bias[c0+3]; }
  #pragma unroll
  for(int j = 0; j < 4; j++){
    int rg = row0 + rb + j;
    if(rg < nrows){
      *(float4*)&out[(size_t)rg * 128 + c0] =
        make_float4(acc[j][0]+b0, acc[j][1]+b1, acc[j][2]+b2v, acc[j][3]+b3);
    }
  }
}

// ---------------- bc = b_in @ W1 (tiny vec-mat) ----------------
__global__ __launch_bounds__(128) void k_vecmat(const float* __restrict__ v,
    const float* __restrict__ W, float* __restrict__ outv){
  int c = threadIdx.x;
  float s = 0.f;
  for(int k = 0; k < 128; k++) s += v[k] * W[k * 128 + c];
  outv[c] = s;
}

// ---------------- projection GEMM: bf16-packed out + fused alpha_s/alpha_d (+opt bias) ----------
// ABF: A is bf16-packed (uint per 2 features) — halves A-read traffic for layer 2.
template<bool ABF>
__global__ __launch_bounds__(256) void k_gemm_proj(const void* __restrict__ Av,
    const float* __restrict__ W, const float* __restrict__ a_src,
    const float* __restrict__ a_dst, const float* __restrict__ bias,
    unsigned int* __restrict__ hb,
    float* __restrict__ alpha_s, float* __restrict__ alpha_d, int nrows){
  __shared__ float Wl[64 * 128];
  __shared__ float Al[32 * 128];
  const int t = threadIdx.x;
  const int row0 = blockIdx.x * 32;
  #pragma unroll
  for(int i = 0; i < 8; i++){
    int idx = t + i * 256;
    int r = idx >> 6, kk = idx & 63;
    int rg = row0 + r; if(rg >= nrows) rg = nrows - 1;
    if(ABF){
      unsigned int v = ((const unsigned int*)Av)[(size_t)rg * 64 + kk];
      Al[r*128 + 2*kk]     = b2f((unsigned short)(v & 0xffffu));
      Al[r*128 + 2*kk + 1] = b2f((unsigned short)(v >> 16));
    } else {
      float2 v = ((const float2*)Av)[(size_t)rg * 64 + kk];
      Al[r*128 + 2*kk] = v.x; Al[r*128 + 2*kk + 1] = v.y;
    }
  }
  const int c0 = (t & 31) * 4;
  const int rb = (t >> 5) * 4;
  float acc[4][4] = {};
  const float4* W4 = (const float4*)W;
  #pragma unroll
  for(int h = 0; h < 2; h++){
    if(h) __syncthreads();
    #pragma unroll
    for(int i = 0; i < 8; i++) ((float4*)Wl)[t + i * 256] = W4[h * 2048 + t + i * 256];
    __syncthreads();
    const int kb = h * 64;
    #pragma unroll 8
    for(int k = 0; k < 64; k++){
      float4 wv = *(const float4*)&Wl[k * 128 + c0];
      float a0 = Al[(rb+0)*128 + kb + k];
      float a1 = Al[(rb+1)*128 + kb + k];
      float a2 = Al[(rb+2)*128 + kb + k];
      float a3 = Al[(rb+3)*128 + kb + k];
      acc[0][0] += a0*wv.x; acc[0][1] += a0*wv.y; acc[0][2] += a0*wv.z; acc[0][3] += a0*wv.w;
      acc[1][0] += a1*wv.x; acc[1][1] += a1*wv.y; acc[1][2] += a1*wv.z; acc[1][3] += a1*wv.w;
      acc[2][0] += a2*wv.x; acc[2][1] += a2*wv.y; acc[2][2] += a2*wv.z; acc[2][3] += a2*wv.w;
      acc[3][0] += a3*wv.x; acc[3][1] += a3*wv.y; acc[3][2] += a3*wv.z; acc[3][3] += a3*wv.w;
    }
  }
  if(bias){   // composite lin_in bias (must precede alpha dots)
    float b0 = bias[c0], b1 = bias[c0+1], b2v = bias[c0+2], b3 = bias[c0+3];
    #pragma unroll
    for(int j = 0; j < 4; j++){
      acc[j][0] += b0; acc[j][1] += b1; acc[j][2] += b2v; acc[j][3] += b3;
    }
  }
  float4 asv = *(const float4*)&a_src[c0];
  float4 adv = *(const float4*)&a_dst[c0];
  #pragma unroll
  for(int j = 0; j < 4; j++){
    int rg = row0 + rb + j;
    float s = acc[j][0]*asv.x + acc[j][1]*asv.y + acc[j][2]*asv.z + acc[j][3]*asv.w;
    float d = acc[j][0]*adv.x + acc[j][1]*adv.y + acc[j][2]*adv.z + acc[j][3]*adv.w;
    #pragma unroll
    for(int o = 16; o; o >>= 1){ s += __shfl_xor(s, o); d += __shfl_xor(d, o); }
    if(rg < nrows){
      if((t & 31) == 0){ alpha_s[rg] = s; alpha_d[rg] = d; }
      uint2 u = make_uint2(pack_bf2(acc[j][0], acc[j][1]), pack_bf2(acc[j][2], acc[j][3]));
      *(uint2*)&hb[(size_t)rg * 64 + (c0 >> 1)] = u;
    }
  }
}

// ---------------- CSR build: hist + 3-phase multi-block scan ----------------
__global__ __launch_bounds__(256) void k_hist(const int* __restrict__ ei, int* __restrict__ deg,
    int E, int Etot){
  int e = blockIdx.x * 256 + threadIdx.x;
  if(e >= Etot) return;
  int dst = (e < E) ? ei[E + e] : (e - E);
  atomicAdd(&deg[dst], 1);
}

__global__ __launch_bounds__(1024) void k_scanA(const int* __restrict__ deg,
    int* __restrict__ rowptr, int* __restrict__ bsum, int n){
  const int t = threadIdx.x;
  const int j0 = blockIdx.x * 4096 + t * 4;
  int v0 = 0, v1 = 0, v2 = 0, v3 = 0;
  if(j0 + 3 < n){
    int4 q = *(const int4*)&deg[j0];
    v0 = q.x; v1 = q.y; v2 = q.z; v3 = q.w;
  } else {
    if(j0     < n) v0 = deg[j0];
    if(j0 + 1 < n) v1 = deg[j0 + 1];
    if(j0 + 2 < n) v2 = deg[j0 + 2];
    if(j0 + 3 < n) v3 = deg[j0 + 3];
  }
  int p1 = v0 + v1, p2 = p1 + v2, tot = p2 + v3;
  const int lane = t & 63, wv = t >> 6;
  int incl = tot;
  #pragma unroll
  for(int off = 1; off < 64; off <<= 1){
    int x = __shfl_up(incl, off);
    if(lane >= off) incl += x;
  }
  __shared__ int wsum[16];
  if(lane == 63) wsum[wv] = incl;
  __syncthreads();
  if(wv == 0){
    int s = (lane < 16) ? wsum[lane] : 0;
    #pragma unroll
    for(int off = 1; off < 16; off <<= 1){
      int x = __shfl_up(s, off);
      if(lane >= off) s += x;
    }
    if(lane < 16) wsum[lane] = s;
  }
  __syncthreads();
  int woff = (wv > 0) ? wsum[wv - 1] : 0;
  int excl = woff + incl - tot;
  if(j0     < n) rowptr[j0 + 1] = excl + v0;
  if(j0 + 1 < n) rowptr[j0 + 2] = excl + p1;
  if(j0 + 2 < n) rowptr[j0 + 3] = excl + p2;
  if(j0 + 3 < n) rowptr[j0 + 4] = excl + tot;
  if(t == 1023) bsum[blockIdx.x] = woff + incl;
}

__global__ __launch_bounds__(64) void k_scanB(int* __restrict__ bsum, int nb){
  int lane = threadIdx.x;
  int v = (lane < nb) ? bsum[lane] : 0;
  int incl = v;
  #pragma unroll
  for(int off = 1; off < 64; off <<= 1){
    int x = __shfl_up(incl, off);
    if(lane >= off) incl += x;
  }
  if(lane < nb) bsum[lane] = incl - v;
}

__global__ __launch_bounds__(256) void k_scanC(int* __restrict__ rowptr,
    const int* __restrict__ bsum, int n){
  int idx = blockIdx.x * 256 + threadIdx.x;
  if(idx == 0) rowptr[0] = 0;
  int i = idx + 1;
  if(i <= n) rowptr[i] += bsum[(i - 1) >> 12];
}

__global__ __launch_bounds__(256) void k_binit(const int* __restrict__ rowptr,
    int* __restrict__ bcur, int n, int nbuck){
  int b = blockIdx.x * 256 + threadIdx.x;
  if(b < nbuck) bcur[b] = rowptr[min(n, b << BSHIFT)];
}

__global__ __launch_bounds__(256) void k_binA(const int* __restrict__ ei,
    int* __restrict__ bcur, uint2* __restrict__ staged, int E, int Etot){
  __shared__ int hist[MAXBUCK];
  __shared__ int scanb[MAXBUCK];
  __shared__ int delta[MAXBUCK];
  __shared__ uint2 buf[4096];     // 32 KB
  const int t = threadIdx.x;
  const int base = blockIdx.x * 4096;
  if(t < MAXBUCK) hist[t] = 0;
  __syncthreads();
  int myb[16], myi[16]; uint2 mye[16];
  #pragma unroll
  for(int k = 0; k < 16; k++){
    int e = base + t + k * 256;
    myb[k] = -1;
    if(e < Etot){
      int src, dst;
      if(e < E){ src = ei[e]; dst = ei[E + e]; }
      else { src = e - E; dst = src; }
      int b = dst >> BSHIFT;
      myi[k] = atomicAdd(&hist[b], 1);
      myb[k] = b;
      mye[k] = make_uint2((unsigned)src, (unsigned)dst);
    }
  }
  __syncthreads();
  if(t < MAXBUCK) scanb[t] = hist[t];
  __syncthreads();
  for(int off = 1; off < MAXBUCK; off <<= 1){
    int v = (t < MAXBUCK && t >= off) ? scanb[t - off] : 0;
    __syncthreads();
    if(t < MAXBUCK) scanb[t] += v;
    __syncthreads();
  }
  if(t < MAXBUCK){
    int excl = scanb[t] - hist[t];
    int gb = (hist[t] > 0) ? atomicAdd(&bcur[t], hist[t]) : 0;
    delta[t] = gb - excl;
    scanb[t] = excl;
  }
  __syncthreads();
  #pragma unroll
  for(int k = 0; k < 16; k++){
    if(myb[k] >= 0) buf[scanb[myb[k]] + myi[k]] = mye[k];
  }
  __syncthreads();
  int total = min(4096, Etot - base);
  for(int i = t; i < total; i += 256){
    uint2 ed = buf[i];
    int b = (int)(ed.y >> BSHIFT);
    staged[i + delta[b]] = ed;     // contiguous runs per bucket
  }
}

__global__ __launch_bounds__(256) void k_binB(const uint2* __restrict__ staged,
    const int* __restrict__ rowptr, int* __restrict__ esrc, int n){
  __shared__ int cur[1 << BSHIFT];
  const int b = blockIdx.x;
  const int n0 = b << BSHIFT;
  const int n1 = min(n, n0 + (1 << BSHIFT));
  const int t = threadIdx.x;
  for(int i = n0 + t; i < n1; i += 256) cur[i - n0] = rowptr[i];
  __syncthreads();
  const int lo = rowptr[n0];
  const int hi = rowptr[n1];
  for(int j = lo + t; j < hi; j += 256){
    uint2 ed = staged[j];
    int pos = atomicAdd(&cur[(int)ed.y - n0], 1);
    esrc[pos] = (int)ed.x;
  }
}

// ---------------- GAT: lane-parallel softmax + single gather walk ----------------
// POOL=false: write bf16-packed h (layer 1).  POOL=true: atomicAdd relu(h) into per-graph pool (layer 2).
template<bool POOL>
__global__ __launch_bounds__(256) void k_gat(const unsigned int* __restrict__ hb,
    const int* __restrict__ rowptr, const int* __restrict__ esrc,
    const float* __restrict__ a_s, const float* __restrict__ a_d,
    const float* __restrict__ bias, unsigned int* __restrict__ hb_out,
    float* __restrict__ pool, const int* __restrict__ batch, int n, int Etot){
  int w = (blockIdx.x * 256 + threadIdx.x) >> 6;
  int lane = threadIdx.x & 63;
  if(w >= n) return;
  int s0 = rowptr[w], s1 = rowptr[w + 1];
  s0 = max(0, min(s0, Etot));
  s1 = max(s0, min(s1, Etot));
  const int deg = s1 - s0;
  const float adv = a_d[w];
  float2 acc0 = make_float2(0.f, 0.f), acc1 = make_float2(0.f, 0.f);
  float2 acc2 = make_float2(0.f, 0.f), acc3 = make_float2(0.f, 0.f);

  if(deg <= 64){
    int srcl = 0; float e = -1e30f;
    if(lane < deg){
      srcl = esrc[s0 + lane];
      srcl = ((unsigned)srcl < (unsigned)n) ? srcl : 0;
      e = a_s[srcl] + adv;
      e = e > 0.f ? e : NEG_SLOPE * e;
    }
    float m = e;
    #pragma unroll
    for(int o = 32; o; o >>= 1) m = fmaxf(m, __shfl_xor(m, o));
    float wgt = (lane < deg) ? __expf(e - m) : 0.f;
    float den = wgt;
    #pragma unroll
    for(int o = 32; o; o >>= 1) den += __shfl_xor(den, o);
    float winv = (den > 0.f) ? wgt / den : 0.f;
    int jj = 0;
    for(; jj + 8 <= deg; jj += 8){
      int   i0 = __shfl(srcl, jj),     i1 = __shfl(srcl, jj + 1);
      int   i2 = __shfl(srcl, jj + 2), i3 = __shfl(srcl, jj + 3);
      int   i4 = __shfl(srcl, jj + 4), i5 = __shfl(srcl, jj + 5);
      int   i6 = __shfl(srcl, jj + 6), i7 = __shfl(srcl, jj + 7);
      float w0 = __shfl(winv, jj),     w1 = __shfl(winv, jj + 1);
      float w2 = __shfl(winv, jj + 2), w3 = __shfl(winv, jj + 3);
      float w4 = __shfl(winv, jj + 4), w5 = __shfl(winv, jj + 5);
      float w6 = __shfl(winv, jj + 6), w7 = __shfl(winv, jj + 7);
      unsigned int u0 = hb[(((unsigned)i0) << 6) + lane];
      unsigned int u1 = hb[(((unsigned)i1) << 6) + lane];
      unsigned int u2 = hb[(((unsigned)i2) << 6) + lane];
      unsigned int u3 = hb[(((unsigned)i3) << 6) + lane];
      unsigned int u4 = hb[(((unsigned)i4) << 6) + lane];
      unsigned int u5 = hb[(((unsigned)i5) << 6) + lane];
      unsigned int u6 = hb[(((unsigned)i6) << 6) + lane];
      unsigned int u7 = hb[(((unsigned)i7) << 6) + lane];
      acc0.x += w0 * b2f((unsigned short)(u0 & 0xffffu)); acc0.y += w0 * b2f((unsigned short)(u0 >> 16));
      acc1.x += w1 * b2f((unsigned short)(u1 & 0xffffu)); acc1.y += w1 * b2f((unsigned short)(u1 >> 16));
      acc2.x += w2 * b2f((unsigned short)(u2 & 0xffffu)); acc2.y += w2 * b2f((unsigned short)(u2 >> 16));
      acc3.x += w3 * b2f((unsigned short)(u3 & 0xffffu)); acc3.y += w3 * b2f((unsigned short)(u3 >> 16));
      acc0.x += w4 * b2f((unsigned short)(u4 & 0xffffu)); acc0.y += w4 * b2f((unsigned short)(u4 >> 16));
      acc1.x += w5 * b2f((unsigned short)(u5 & 0xffffu)); acc1.y += w5 * b2f((unsigned short)(u5 >> 16));
      acc2.x += w6 * b2f((unsigned short)(u6 & 0xffffu)); acc2.y += w6 * b2f((unsigned short)(u6 >> 16));
      acc3.x += w7 * b2f((unsigned short)(u7 & 0xffffu)); acc3.y += w7 * b2f((unsigned short)(u7 >> 16));
    }
    for(; jj < deg; jj++){
      int   ci = __shfl(srcl, jj);
      float wv = __shfl(winv, jj);
      unsigned int u = hb[(((unsigned)ci) << 6) + lane];
      acc0.x += wv * b2f((unsigned short)(u & 0xffffu));
      acc0.y += wv * b2f((unsigned short)(u >> 16));
    }
  } else {
    float m = -1e30f;
    for(int j = s0 + lane; j < s1; j += 64){
      int s = esrc[j]; s = ((unsigned)s < (unsigned)n) ? s : 0;
      float e = a_s[s] + adv;
      e = e > 0.f ? e : NEG_SLOPE * e;
      m = fmaxf(m, e);
    }
    #pragma unroll
    for(int o = 32; o; o >>= 1) m = fmaxf(m, __shfl_xor(m, o));
    float den = 0.f;
    for(int j = s0 + lane; j < s1; j += 64){
      int s = esrc[j]; s = ((unsigned)s < (unsigned)n) ? s : 0;
      float e = a_s[s] + adv;
      e = e > 0.f ? e : NEG_SLOPE * e;
      den += __expf(e - m);
    }
    #pragma unroll
    for(int o = 32; o; o >>= 1) den += __shfl_xor(den, o);
    float inv = (den > 0.f) ? 1.f / den : 0.f;
    for(int j = s0; j < s1; j++){
      int s = esrc[j]; s = ((unsigned)s < (unsigned)n) ? s : 0;
      float e = a_s[s] + adv;
      e = e > 0.f ? e : NEG_SLOPE * e;
      float wv = __expf(e - m) * inv;
      unsigned int u = hb[(((unsigned)s) << 6) + lane];
      acc0.x += wv * b2f((unsigned short)(u & 0xffffu));
      acc0.y += wv * b2f((unsigned short)(u >> 16));
    }
  }
  float2 bl = ((const float2*)bias)[lane];
  float ox = (acc0.x + acc1.x) + (acc2.x + acc3.x) + bl.x;
  float oy = (acc0.y + acc1.y) + (acc2.y + acc3.y) + bl.y;
  ox = 0.5f * (ox + fabsf(ox));   // NaN-transparent relu
  oy = 0.5f * (oy + fabsf(oy));
  if(POOL){
    int g = batch[w];
    atomicAdd(&pool[g * 128 + 2 * lane], ox);
    atomicAdd(&pool[g * 128 + 2 * lane + 1], oy);
  } else {
    hb_out[(size_t)w * 64 + lane] = pack_bf2(ox, oy);
  }
}

// ---------------- graph bounds ----------------
__global__ __launch_bounds__(256) void k_bounds(const int* __restrict__ batch,
    int* __restrict__ gs, int* __restrict__ ge, int n){
  int i = blockIdx.x * 256 + threadIdx.x;
  if(i >= n) return;
  int g = batch[i];
  if(i == 0){
    gs[g] = 0;
  } else {
    int gp = batch[i - 1];
    if(gp != g){ gs[g] = i; ge[gp] = i; }
  }
  if(i == n - 1) ge[g] = n;
}

// ---------------- head: out[g] = (pool[g]/cnt) . out_w + out_b ----------------
__global__ __launch_bounds__(128) void k_head(const float* __restrict__ pool,
    const int* __restrict__ gs, const int* __restrict__ ge,
    const float* __restrict__ out_w, const float* __restrict__ out_b,
    float* __restrict__ out, int n){
  const int g = blockIdx.x, f = threadIdx.x;
  int s = gs[g], e = ge[g];
  s = max(0, min(s, n)); e = max(s, min(e, n));
  int c = e - s;
  float invc = (c > 0) ? 1.f / (float)c : 0.f;
  float v = pool[g * 128 + f] * invc * out_w[f];
  #pragma unroll
  for(int o = 32; o; o >>= 1) v += __shfl_xor(v, o);
  __shared__ float part[2];
  if((f & 63) == 0) part[f >> 6] = v;
  __syncthreads();
  if(f == 0) out[g] = part[0] + part[1] + out_b[0];
}

extern "C" void kernel_launch(void* const* d_in, const int* in_sizes, int n_in,
                              void* d_out, int out_size, void* d_ws, size_t ws_size,
                              hipStream_t stream){
  const float* x     = (const float*)d_in[0];
  const int*   ei    = (const int*)d_in[1];
  const int*   batch = (const int*)d_in[2];
  const float* lin_w = (const float*)d_in[3];
  const float* lin_b = (const float*)d_in[4];
  const float* w1    = (const float*)d_in[5];
  const float* as1   = (const float*)d_in[6];
  const float* ad1   = (const float*)d_in[7];
  const float* b1    = (const float*)d_in[8];
  const float* w2    = (const float*)d_in[9];
  const float* as2   = (const float*)d_in[10];
  const float* ad2   = (const float*)d_in[11];
  const float* b2    = (const float*)d_in[12];
  const float* ow    = (const float*)d_in[13];
  const float* ob    = (const float*)d_in[14];
  float* out = (float*)d_out;

  const int N = in_sizes[0] / 128;
  const int E = in_sizes[1] / 2;
  const int Etot = E + N;
  const int G = out_size;
  const int nbuck = (N + (1 << BSHIFT) - 1) >> BSHIFT;
  const int nsb = (N + 4095) / 4096;     // scan blocks (<=64)

  char* p = (char*)d_ws;
  int*   deg     = (int*)p;   p += (size_t)(N + 1) * 4;
  int*   rowptr  = (int*)p;   p += (size_t)(N + 1) * 4;
  int*   bcur    = (int*)p;   p += (size_t)MAXBUCK * 4;
  int*   bsum    = (int*)p;   p += (size_t)64 * 4;
  int*   gs      = (int*)p;   p += (size_t)G * 4;
  int*   ge      = (int*)p;   p += (size_t)G * 4;
  float* pool    = (float*)p; p += (size_t)G * 128 * 4;
  float* alpha_s = (float*)p; p += (size_t)N * 4;
  float* alpha_d = (float*)p; p += (size_t)N * 4;
  float* Wc      = (float*)p; p += (size_t)128 * 128 * 4;  // Win@W1 composite
  float* bc      = (float*)p; p += (size_t)128 * 4;        // b_in@W1
  int*   esrc    = (int*)p;   p += (size_t)Etot * 4;
  uint2* staged  = (uint2*)p; p += (size_t)Etot * 8;
  unsigned int* hb  = (unsigned int*)p; p += (size_t)N * 64 * 4;  // projection, bf16-packed
  unsigned int* hb2 = (unsigned int*)p; p += (size_t)N * 64 * 4;  // h1, bf16-packed

  const int ebl = (Etot + 255) / 256;
  k_init<<<(N + 256) / 256, 256, 0, stream>>>(deg, gs, ge, pool, N + 1, G);
  k_hist<<<ebl, 256, 0, stream>>>(ei, deg, E, Etot);
  k_scanA<<<nsb, 1024, 0, stream>>>(deg, rowptr, bsum, N);
  k_scanB<<<1, 64, 0, stream>>>(bsum, nsb);
  k_scanC<<<(N + 255) / 256, 256, 0, stream>>>(rowptr, bsum, N);
  k_binit<<<(nbuck + 255) / 256, 256, 0, stream>>>(rowptr, bcur, N, nbuck);
  k_binA<<<(Etot + 4095) / 4096, 256, 0, stream>>>(ei, bcur, staged, E, Etot);
  k_binB<<<nbuck, 256, 0, stream>>>(staged, rowptr, esrc, N);
  k_bounds<<<(N + 255) / 256, 256, 0, stream>>>(batch, gs, ge, N);

  // composite: proj1 = x @ (Win@W1) + b_in@W1  (no nonlinearity between lin_in and proj1)
  k_gemm<<<4, 256, 0, stream>>>(lin_w, w1, nullptr, Wc, 128);
  k_vecmat<<<1, 128, 0, stream>>>(lin_b, w1, bc);

  const int gbl = (N + 31) / 32;
  const int wbl = (N + 3) / 4;

  k_gemm_proj<false><<<gbl, 256, 0, stream>>>(x, Wc, as1, ad1, bc, hb, alpha_s, alpha_d, N);
  k_gat<false><<<wbl, 256, 0, stream>>>(hb, rowptr, esrc, alpha_s, alpha_d, b1,
                                        hb2, nullptr, nullptr, N, Etot);
  k_gemm_proj<true><<<gbl, 256, 0, stream>>>(hb2, w2, as2, ad2, nullptr, hb, alpha_s, alpha_d, N);
  k_gat<true><<<wbl, 256, 0, stream>>>(hb, rowptr, esrc, alpha_s, alpha_d, b2,
                                       nullptr, pool, batch, N, Etot);
  k_head<<<G, 128, 0, stream>>>(pool, gs, ge, ow, ob, out, N);
}

// Round 16
// 364.844 us; speedup vs baseline: 1.3476x; 1.3476x over previous
//
#include <hip/hip_runtime.h>
#include <hip/hip_bf16.h>

#define NEG_SLOPE 0.2f
#define BSHIFT 9                 // 512 nodes per bucket
#define MAXBUCK 128              // covers N up to 65536

static __device__ __forceinline__ float b2f(unsigned short u){
  return __uint_as_float(((unsigned int)u) << 16);
}
static __device__ __forceinline__ unsigned int pack_bf2(float a, float b){
  unsigned int ua = __float_as_uint(a);
  unsigned int ub = __float_as_uint(b);
  unsigned int ra = (ua + 0x7fffu + ((ua >> 16) & 1u)) >> 16;   // RNE
  unsigned int rb = (ub + 0x7fffu + ((ub >> 16) & 1u)) >> 16;
  return ra | (rb << 16);
}

// ---------------- workspace init ----------------
__global__ __launch_bounds__(256) void k_init(int* deg, int* gs, int* ge, int n1, int G){
  int i = blockIdx.x * 256 + threadIdx.x;
  if(i < n1) deg[i] = 0;
  if(i < G){ gs[i] = 0x7fffffff; ge[i] = 0; }
}

// ---------------- GEMM: f32 out (+optional bias). Round-11 inner loop: ~100 VGPR, no spill.
// NOTE: 4-k float4-A blocking (round 12) spilled to scratch (256 VGPR, 2 GB traffic) — do not reintroduce.
// NOTE: atomicAdd pooling in k_gat (round 15) serialized 780-deep on 8192 addrs → 220 µs — do not reintroduce.
__global__ __launch_bounds__(256) void k_gemm(const float* __restrict__ A,
    const float* __restrict__ W, const float* __restrict__ bias,
    float* __restrict__ out, int nrows){
  __shared__ float Wl[64 * 128];
  __shared__ float Al[32 * 128];
  const int t = threadIdx.x;
  const int row0 = blockIdx.x * 32;
  #pragma unroll
  for(int i = 0; i < 8; i++){
    int idx = t + i * 256;
    int r = idx >> 6, kk = idx & 63;
    int rg = row0 + r; if(rg >= nrows) rg = nrows - 1;
    ((float2*)Al)[r * 64 + kk] = ((const float2*)A)[(size_t)rg * 64 + kk];
  }
  const int c0 = (t & 31) * 4;
  const int rb = (t >> 5) * 4;
  float acc[4][4] = {};
  const float4* W4 = (const float4*)W;
  #pragma unroll
  for(int h = 0; h < 2; h++){
    if(h) __syncthreads();
    #pragma unroll
    for(int i = 0; i < 8; i++) ((float4*)Wl)[t + i * 256] = W4[h * 2048 + t + i * 256];
    __syncthreads();
    const int kb = h * 64;
    #pragma unroll 8
    for(int k = 0; k < 64; k++){
      float4 wv = *(const float4*)&Wl[k * 128 + c0];
      float a0 = Al[(rb+0)*128 + kb + k];
      float a1 = Al[(rb+1)*128 + kb + k];
      float a2 = Al[(rb+2)*128 + kb + k];
      float a3 = Al[(rb+3)*128 + kb + k];
      acc[0][0] += a0*wv.x; acc[0][1] += a0*wv.y; acc[0][2] += a0*wv.z; acc[0][3] += a0*wv.w;
      acc[1][0] += a1*wv.x; acc[1][1] += a1*wv.y; acc[1][2] += a1*wv.z; acc[1][3] += a1*wv.w;
      acc[2][0] += a2*wv.x; acc[2][1] += a2*wv.y; acc[2][2] += a2*wv.z; acc[2][3] += a2*wv.w;
      acc[3][0] += a3*wv.x; acc[3][1] += a3*wv.y; acc[3][2] += a3*wv.z; acc[3][3] += a3*wv.w;
    }
  }
  float b0 = 0.f, b1 = 0.f, b2v = 0.f, b3 = 0.f;
  if(bias){ b0 = bias[c0]; b1 = bias[c0+1]; b2v = bias[c0+2]; b3 = bias[c0+3]; }
  #pragma unroll
  for(int j = 0; j < 4; j++){
    int rg = row0 + rb + j;
    if(rg < nrows){
      *(float4*)&out[(size_t)rg * 128 + c0] =
        make_float4(acc[j][0]+b0, acc[j][1]+b1, acc[j][2]+b2v, acc[j][3]+b3);
    }
  }
}

// ---------------- bc = b_in @ W1 (tiny vec-mat) ----------------
__global__ __launch_bounds__(128) void k_vecmat(const float* __restrict__ v,
    const float* __restrict__ W, float* __restrict__ outv){
  int c = threadIdx.x;
  float s = 0.f;
  for(int k = 0; k < 128; k++) s += v[k] * W[k * 128 + c];
  outv[c] = s;
}

// ---------------- projection GEMM: bf16-packed out + fused alpha_s/alpha_d (+opt bias) ----------
// ABF: A is bf16-packed (uint per 2 features) — halves A-read traffic for layer 2.
template<bool ABF>
__global__ __launch_bounds__(256) void k_gemm_proj(const void* __restrict__ Av,
    const float* __restrict__ W, const float* __restrict__ a_src,
    const float* __restrict__ a_dst, const float* __restrict__ bias,
    unsigned int* __restrict__ hb,
    float* __restrict__ alpha_s, float* __restrict__ alpha_d, int nrows){
  __shared__ float Wl[64 * 128];
  __shared__ float Al[32 * 128];
  const int t = threadIdx.x;
  const int row0 = blockIdx.x * 32;
  #pragma unroll
  for(int i = 0; i < 8; i++){
    int idx = t + i * 256;
    int r = idx >> 6, kk = idx & 63;
    int rg = row0 + r; if(rg >= nrows) rg = nrows - 1;
    if(ABF){
      unsigned int v = ((const unsigned int*)Av)[(size_t)rg * 64 + kk];
      Al[r*128 + 2*kk]     = b2f((unsigned short)(v & 0xffffu));
      Al[r*128 + 2*kk + 1] = b2f((unsigned short)(v >> 16));
    } else {
      float2 v = ((const float2*)Av)[(size_t)rg * 64 + kk];
      Al[r*128 + 2*kk] = v.x; Al[r*128 + 2*kk + 1] = v.y;
    }
  }
  const int c0 = (t & 31) * 4;
  const int rb = (t >> 5) * 4;
  float acc[4][4] = {};
  const float4* W4 = (const float4*)W;
  #pragma unroll
  for(int h = 0; h < 2; h++){
    if(h) __syncthreads();
    #pragma unroll
    for(int i = 0; i < 8; i++) ((float4*)Wl)[t + i * 256] = W4[h * 2048 + t + i * 256];
    __syncthreads();
    const int kb = h * 64;
    #pragma unroll 8
    for(int k = 0; k < 64; k++){
      float4 wv = *(const float4*)&Wl[k * 128 + c0];
      float a0 = Al[(rb+0)*128 + kb + k];
      float a1 = Al[(rb+1)*128 + kb + k];
      float a2 = Al[(rb+2)*128 + kb + k];
      float a3 = Al[(rb+3)*128 + kb + k];
      acc[0][0] += a0*wv.x; acc[0][1] += a0*wv.y; acc[0][2] += a0*wv.z; acc[0][3] += a0*wv.w;
      acc[1][0] += a1*wv.x; acc[1][1] += a1*wv.y; acc[1][2] += a1*wv.z; acc[1][3] += a1*wv.w;
      acc[2][0] += a2*wv.x; acc[2][1] += a2*wv.y; acc[2][2] += a2*wv.z; acc[2][3] += a2*wv.w;
      acc[3][0] += a3*wv.x; acc[3][1] += a3*wv.y; acc[3][2] += a3*wv.z; acc[3][3] += a3*wv.w;
    }
  }
  if(bias){   // composite lin_in bias (must precede alpha dots)
    float b0 = bias[c0], b1 = bias[c0+1], b2v = bias[c0+2], b3 = bias[c0+3];
    #pragma unroll
    for(int j = 0; j < 4; j++){
      acc[j][0] += b0; acc[j][1] += b1; acc[j][2] += b2v; acc[j][3] += b3;
    }
  }
  float4 asv = *(const float4*)&a_src[c0];
  float4 adv = *(const float4*)&a_dst[c0];
  #pragma unroll
  for(int j = 0; j < 4; j++){
    int rg = row0 + rb + j;
    float s = acc[j][0]*asv.x + acc[j][1]*asv.y + acc[j][2]*asv.z + acc[j][3]*asv.w;
    float d = acc[j][0]*adv.x + acc[j][1]*adv.y + acc[j][2]*adv.z + acc[j][3]*adv.w;
    #pragma unroll
    for(int o = 16; o; o >>= 1){ s += __shfl_xor(s, o); d += __shfl_xor(d, o); }
    if(rg < nrows){
      if((t & 31) == 0){ alpha_s[rg] = s; alpha_d[rg] = d; }
      uint2 u = make_uint2(pack_bf2(acc[j][0], acc[j][1]), pack_bf2(acc[j][2], acc[j][3]));
      *(uint2*)&hb[(size_t)rg * 64 + (c0 >> 1)] = u;
    }
  }
}

// ---------------- CSR build: hist + 3-phase multi-block scan ----------------
__global__ __launch_bounds__(256) void k_hist(const int* __restrict__ ei, int* __restrict__ deg,
    int E, int Etot){
  int e = blockIdx.x * 256 + threadIdx.x;
  if(e >= Etot) return;
  int dst = (e < E) ? ei[E + e] : (e - E);
  atomicAdd(&deg[dst], 1);
}

__global__ __launch_bounds__(1024) void k_scanA(const int* __restrict__ deg,
    int* __restrict__ rowptr, int* __restrict__ bsum, int n){
  const int t = threadIdx.x;
  const int j0 = blockIdx.x * 4096 + t * 4;
  int v0 = 0, v1 = 0, v2 = 0, v3 = 0;
  if(j0 + 3 < n){
    int4 q = *(const int4*)&deg[j0];
    v0 = q.x; v1 = q.y; v2 = q.z; v3 = q.w;
  } else {
    if(j0     < n) v0 = deg[j0];
    if(j0 + 1 < n) v1 = deg[j0 + 1];
    if(j0 + 2 < n) v2 = deg[j0 + 2];
    if(j0 + 3 < n) v3 = deg[j0 + 3];
  }
  int p1 = v0 + v1, p2 = p1 + v2, tot = p2 + v3;
  const int lane = t & 63, wv = t >> 6;
  int incl = tot;
  #pragma unroll
  for(int off = 1; off < 64; off <<= 1){
    int x = __shfl_up(incl, off);
    if(lane >= off) incl += x;
  }
  __shared__ int wsum[16];
  if(lane == 63) wsum[wv] = incl;
  __syncthreads();
  if(wv == 0){
    int s = (lane < 16) ? wsum[lane] : 0;
    #pragma unroll
    for(int off = 1; off < 16; off <<= 1){
      int x = __shfl_up(s, off);
      if(lane >= off) s += x;
    }
    if(lane < 16) wsum[lane] = s;
  }
  __syncthreads();
  int woff = (wv > 0) ? wsum[wv - 1] : 0;
  int excl = woff + incl - tot;
  if(j0     < n) rowptr[j0 + 1] = excl + v0;
  if(j0 + 1 < n) rowptr[j0 + 2] = excl + p1;
  if(j0 + 2 < n) rowptr[j0 + 3] = excl + p2;
  if(j0 + 3 < n) rowptr[j0 + 4] = excl + tot;
  if(t == 1023) bsum[blockIdx.x] = woff + incl;
}

__global__ __launch_bounds__(64) void k_scanB(int* __restrict__ bsum, int nb){
  int lane = threadIdx.x;
  int v = (lane < nb) ? bsum[lane] : 0;
  int incl = v;
  #pragma unroll
  for(int off = 1; off < 64; off <<= 1){
    int x = __shfl_up(incl, off);
    if(lane >= off) incl += x;
  }
  if(lane < nb) bsum[lane] = incl - v;
}

__global__ __launch_bounds__(256) void k_scanC(int* __restrict__ rowptr,
    const int* __restrict__ bsum, int n){
  int idx = blockIdx.x * 256 + threadIdx.x;
  if(idx == 0) rowptr[0] = 0;
  int i = idx + 1;
  if(i <= n) rowptr[i] += bsum[(i - 1) >> 12];
}

__global__ __launch_bounds__(256) void k_binit(const int* __restrict__ rowptr,
    int* __restrict__ bcur, int n, int nbuck){
  int b = blockIdx.x * 256 + threadIdx.x;
  if(b < nbuck) bcur[b] = rowptr[min(n, b << BSHIFT)];
}

__global__ __launch_bounds__(256) void k_binA(const int* __restrict__ ei,
    int* __restrict__ bcur, uint2* __restrict__ staged, int E, int Etot){
  __shared__ int hist[MAXBUCK];
  __shared__ int scanb[MAXBUCK];
  __shared__ int delta[MAXBUCK];
  __shared__ uint2 buf[4096];     // 32 KB
  const int t = threadIdx.x;
  const int base = blockIdx.x * 4096;
  if(t < MAXBUCK) hist[t] = 0;
  __syncthreads();
  int myb[16], myi[16]; uint2 mye[16];
  #pragma unroll
  for(int k = 0; k < 16; k++){
    int e = base + t + k * 256;
    myb[k] = -1;
    if(e < Etot){
      int src, dst;
      if(e < E){ src = ei[e]; dst = ei[E + e]; }
      else { src = e - E; dst = src; }
      int b = dst >> BSHIFT;
      myi[k] = atomicAdd(&hist[b], 1);
      myb[k] = b;
      mye[k] = make_uint2((unsigned)src, (unsigned)dst);
    }
  }
  __syncthreads();
  if(t < MAXBUCK) scanb[t] = hist[t];
  __syncthreads();
  for(int off = 1; off < MAXBUCK; off <<= 1){
    int v = (t < MAXBUCK && t >= off) ? scanb[t - off] : 0;
    __syncthreads();
    if(t < MAXBUCK) scanb[t] += v;
    __syncthreads();
  }
  if(t < MAXBUCK){
    int excl = scanb[t] - hist[t];
    int gb = (hist[t] > 0) ? atomicAdd(&bcur[t], hist[t]) : 0;
    delta[t] = gb - excl;
    scanb[t] = excl;
  }
  __syncthreads();
  #pragma unroll
  for(int k = 0; k < 16; k++){
    if(myb[k] >= 0) buf[scanb[myb[k]] + myi[k]] = mye[k];
  }
  __syncthreads();
  int total = min(4096, Etot - base);
  for(int i = t; i < total; i += 256){
    uint2 ed = buf[i];
    int b = (int)(ed.y >> BSHIFT);
    staged[i + delta[b]] = ed;     // contiguous runs per bucket
  }
}

__global__ __launch_bounds__(256) void k_binB(const uint2* __restrict__ staged,
    const int* __restrict__ rowptr, int* __restrict__ esrc, int n){
  __shared__ int cur[1 << BSHIFT];
  const int b = blockIdx.x;
  const int n0 = b << BSHIFT;
  const int n1 = min(n, n0 + (1 << BSHIFT));
  const int t = threadIdx.x;
  for(int i = n0 + t; i < n1; i += 256) cur[i - n0] = rowptr[i];
  __syncthreads();
  const int lo = rowptr[n0];
  const int hi = rowptr[n1];
  for(int j = lo + t; j < hi; j += 256){
    uint2 ed = staged[j];
    int pos = atomicAdd(&cur[(int)ed.y - n0], 1);
    esrc[pos] = (int)ed.x;
  }
}

// ---------------- GAT: lane-parallel softmax + single gather walk, bf16 out ----------------
__global__ __launch_bounds__(256) void k_gat(const unsigned int* __restrict__ hb,
    const int* __restrict__ rowptr, const int* __restrict__ esrc,
    const float* __restrict__ a_s, const float* __restrict__ a_d,
    const float* __restrict__ bias, unsigned int* __restrict__ hb_out, int n, int Etot){
  int w = (blockIdx.x * 256 + threadIdx.x) >> 6;
  int lane = threadIdx.x & 63;
  if(w >= n) return;
  int s0 = rowptr[w], s1 = rowptr[w + 1];
  s0 = max(0, min(s0, Etot));
  s1 = max(s0, min(s1, Etot));
  const int deg = s1 - s0;
  const float adv = a_d[w];
  float2 acc0 = make_float2(0.f, 0.f), acc1 = make_float2(0.f, 0.f);
  float2 acc2 = make_float2(0.f, 0.f), acc3 = make_float2(0.f, 0.f);

  if(deg <= 64){
    int srcl = 0; float e = -1e30f;
    if(lane < deg){
      srcl = esrc[s0 + lane];
      srcl = ((unsigned)srcl < (unsigned)n) ? srcl : 0;
      e = a_s[srcl] + adv;
      e = e > 0.f ? e : NEG_SLOPE * e;
    }
    float m = e;
    #pragma unroll
    for(int o = 32; o; o >>= 1) m = fmaxf(m, __shfl_xor(m, o));
    float wgt = (lane < deg) ? __expf(e - m) : 0.f;
    float den = wgt;
    #pragma unroll
    for(int o = 32; o; o >>= 1) den += __shfl_xor(den, o);
    float winv = (den > 0.f) ? wgt / den : 0.f;
    int jj = 0;
    for(; jj + 8 <= deg; jj += 8){
      int   i0 = __shfl(srcl, jj),     i1 = __shfl(srcl, jj + 1);
      int   i2 = __shfl(srcl, jj + 2), i3 = __shfl(srcl, jj + 3);
      int   i4 = __shfl(srcl, jj + 4), i5 = __shfl(srcl, jj + 5);
      int   i6 = __shfl(srcl, jj + 6), i7 = __shfl(srcl, jj + 7);
      float w0 = __shfl(winv, jj),     w1 = __shfl(winv, jj + 1);
      float w2 = __shfl(winv, jj + 2), w3 = __shfl(winv, jj + 3);
      float w4 = __shfl(winv, jj + 4), w5 = __shfl(winv, jj + 5);
      float w6 = __shfl(winv, jj + 6), w7 = __shfl(winv, jj + 7);
      unsigned int u0 = hb[(((unsigned)i0) << 6) + lane];
      unsigned int u1 = hb[(((unsigned)i1) << 6) + lane];
      unsigned int u2 = hb[(((unsigned)i2) << 6) + lane];
      unsigned int u3 = hb[(((unsigned)i3) << 6) + lane];
      unsigned int u4 = hb[(((unsigned)i4) << 6) + lane];
      unsigned int u5 = hb[(((unsigned)i5) << 6) + lane];
      unsigned int u6 = hb[(((unsigned)i6) << 6) + lane];
      unsigned int u7 = hb[(((unsigned)i7) << 6) + lane];
      acc0.x += w0 * b2f((unsigned short)(u0 & 0xffffu)); acc0.y += w0 * b2f((unsigned short)(u0 >> 16));
      acc1.x += w1 * b2f((unsigned short)(u1 & 0xffffu)); acc1.y += w1 * b2f((unsigned short)(u1 >> 16));
      acc2.x += w2 * b2f((unsigned short)(u2 & 0xffffu)); acc2.y += w2 * b2f((unsigned short)(u2 >> 16));
      acc3.x += w3 * b2f((unsigned short)(u3 & 0xffffu)); acc3.y += w3 * b2f((unsigned short)(u3 >> 16));
      acc0.x += w4 * b2f((unsigned short)(u4 & 0xffffu)); acc0.y += w4 * b2f((unsigned short)(u4 >> 16));
      acc1.x += w5 * b2f((unsigned short)(u5 & 0xffffu)); acc1.y += w5 * b2f((unsigned short)(u5 >> 16));
      acc2.x += w6 * b2f((unsigned short)(u6 & 0xffffu)); acc2.y += w6 * b2f((unsigned short)(u6 >> 16));
      acc3.x += w7 * b2f((unsigned short)(u7 & 0xffffu)); acc3.y += w7 * b2f((unsigned short)(u7 >> 16));
    }
    for(; jj < deg; jj++){
      int   ci = __shfl(srcl, jj);
      float wv = __shfl(winv, jj);
      unsigned int u = hb[(((unsigned)ci) << 6) + lane];
      acc0.x += wv * b2f((unsigned short)(u & 0xffffu));
      acc0.y += wv * b2f((unsigned short)(u >> 16));
    }
  } else {
    float m = -1e30f;
    for(int j = s0 + lane; j < s1; j += 64){
      int s = esrc[j]; s = ((unsigned)s < (unsigned)n) ? s : 0;
      float e = a_s[s] + adv;
      e = e > 0.f ? e : NEG_SLOPE * e;
      m = fmaxf(m, e);
    }
    #pragma unroll
    for(int o = 32; o; o >>= 1) m = fmaxf(m, __shfl_xor(m, o));
    float den = 0.f;
    for(int j = s0 + lane; j < s1; j += 64){
      int s = esrc[j]; s = ((unsigned)s < (unsigned)n) ? s : 0;
      float e = a_s[s] + adv;
      e = e > 0.f ? e : NEG_SLOPE * e;
      den += __expf(e - m);
    }
    #pragma unroll
    for(int o = 32; o; o >>= 1) den += __shfl_xor(den, o);
    float inv = (den > 0.f) ? 1.f / den : 0.f;
    for(int j = s0; j < s1; j++){
      int s = esrc[j]; s = ((unsigned)s < (unsigned)n) ? s : 0;
      float e = a_s[s] + adv;
      e = e > 0.f ? e : NEG_SLOPE * e;
      float wv = __expf(e - m) * inv;
      unsigned int u = hb[(((unsigned)s) << 6) + lane];
      acc0.x += wv * b2f((unsigned short)(u & 0xffffu));
      acc0.y += wv * b2f((unsigned short)(u >> 16));
    }
  }
  float2 bl = ((const float2*)bias)[lane];
  float ox = (acc0.x + acc1.x) + (acc2.x + acc3.x) + bl.x;
  float oy = (acc0.y + acc1.y) + (acc2.y + acc3.y) + bl.y;
  ox = 0.5f * (ox + fabsf(ox));   // NaN-transparent relu
  oy = 0.5f * (oy + fabsf(oy));
  hb_out[(size_t)w * 64 + lane] = pack_bf2(ox, oy);
}

// ---------------- graph bounds ----------------
__global__ __launch_bounds__(256) void k_bounds(const int* __restrict__ batch,
    int* __restrict__ gs, int* __restrict__ ge, int n){
  int i = blockIdx.x * 256 + threadIdx.x;
  if(i >= n) return;
  int g = batch[i];
  if(i == 0){
    gs[g] = 0;
  } else {
    int gp = batch[i - 1];
    if(gp != g){ gs[g] = i; ge[gp] = i; }
  }
  if(i == n - 1) ge[g] = n;
}

// ---------------- mean-pool (bf16 h) + fused head ----------------
__global__ __launch_bounds__(512) void k_poolout(const unsigned int* __restrict__ h2,
    const int* __restrict__ gs, const int* __restrict__ ge,
    const float* __restrict__ out_w, const float* __restrict__ out_b,
    float* __restrict__ out, int n){
  const int g = blockIdx.x;
  const int t = threadIdx.x;
  const int f2 = t & 63;          // packed-uint column (features 2*f2, 2*f2+1)
  const int rr = t >> 6;          // row phase 0..7
  int s = gs[g], e = ge[g];
  s = max(0, min(s, n)); e = max(s, min(e, n));
  float sx = 0.f, sy = 0.f;
  for(int i = s + rr; i < e; i += 8){
    unsigned int u = h2[(size_t)i * 64 + f2];
    sx += b2f((unsigned short)(u & 0xffffu));
    sy += b2f((unsigned short)(u >> 16));
  }
  __shared__ float part[8 * 128];
  part[rr * 128 + 2 * f2]     = sx;
  part[rr * 128 + 2 * f2 + 1] = sy;
  __syncthreads();
  __shared__ float red[2];
  if(t < 128){
    float tot = 0.f;
    #pragma unroll
    for(int r = 0; r < 8; r++) tot += part[r * 128 + t];
    int c = e - s;
    float invc = (c > 0) ? 1.f / (float)c : 0.f;
    float v = tot * invc * out_w[t];
    #pragma unroll
    for(int o = 32; o; o >>= 1) v += __shfl_xor(v, o);
    if((t & 63) == 0) red[t >> 6] = v;
  }
  __syncthreads();
  if(t == 0) out[g] = red[0] + red[1] + out_b[0];
}

extern "C" void kernel_launch(void* const* d_in, const int* in_sizes, int n_in,
                              void* d_out, int out_size, void* d_ws, size_t ws_size,
                              hipStream_t stream){
  const float* x     = (const float*)d_in[0];
  const int*   ei    = (const int*)d_in[1];
  const int*   batch = (const int*)d_in[2];
  const float* lin_w = (const float*)d_in[3];
  const float* lin_b = (const float*)d_in[4];
  const float* w1    = (const float*)d_in[5];
  const float* as1   = (const float*)d_in[6];
  const float* ad1   = (const float*)d_in[7];
  const float* b1    = (const float*)d_in[8];
  const float* w2    = (const float*)d_in[9];
  const float* as2   = (const float*)d_in[10];
  const float* ad2   = (const float*)d_in[11];
  const float* b2    = (const float*)d_in[12];
  const float* ow    = (const float*)d_in[13];
  const float* ob    = (const float*)d_in[14];
  float* out = (float*)d_out;

  const int N = in_sizes[0] / 128;
  const int E = in_sizes[1] / 2;
  const int Etot = E + N;
  const int G = out_size;
  const int nbuck = (N + (1 << BSHIFT) - 1) >> BSHIFT;
  const int nsb = (N + 4095) / 4096;     // scan blocks (<=64)

  char* p = (char*)d_ws;
  int*   deg     = (int*)p;   p += (size_t)(N + 1) * 4;
  int*   rowptr  = (int*)p;   p += (size_t)(N + 1) * 4;
  int*   bcur    = (int*)p;   p += (size_t)MAXBUCK * 4;
  int*   bsum    = (int*)p;   p += (size_t)64 * 4;
  int*   gs      = (int*)p;   p += (size_t)G * 4;
  int*   ge      = (int*)p;   p += (size_t)G * 4;
  float* alpha_s = (float*)p; p += (size_t)N * 4;
  float* alpha_d = (float*)p; p += (size_t)N * 4;
  float* Wc      = (float*)p; p += (size_t)128 * 128 * 4;  // Win@W1 composite
  float* bc      = (float*)p; p += (size_t)128 * 4;        // b_in@W1
  int*   esrc    = (int*)p;   p += (size_t)Etot * 4;
  uint2* staged  = (uint2*)p; p += (size_t)Etot * 8;
  unsigned int* hb  = (unsigned int*)p; p += (size_t)N * 64 * 4;  // projection, bf16-packed
  unsigned int* hb2 = (unsigned int*)p; p += (size_t)N * 64 * 4;  // h1 / h2, bf16-packed

  const int ebl = (Etot + 255) / 256;
  k_init<<<(N + 256) / 256, 256, 0, stream>>>(deg, gs, ge, N + 1, G);
  k_hist<<<ebl, 256, 0, stream>>>(ei, deg, E, Etot);
  k_scanA<<<nsb, 1024, 0, stream>>>(deg, rowptr, bsum, N);
  k_scanB<<<1, 64, 0, stream>>>(bsum, nsb);
  k_scanC<<<(N + 255) / 256, 256, 0, stream>>>(rowptr, bsum, N);
  k_binit<<<(nbuck + 255) / 256, 256, 0, stream>>>(rowptr, bcur, N, nbuck);
  k_binA<<<(Etot + 4095) / 4096, 256, 0, stream>>>(ei, bcur, staged, E, Etot);
  k_binB<<<nbuck, 256, 0, stream>>>(staged, rowptr, esrc, N);
  k_bounds<<<(N + 255) / 256, 256, 0, stream>>>(batch, gs, ge, N);

  // composite: proj1 = x @ (Win@W1) + b_in@W1  (no nonlinearity between lin_in and proj1)
  k_gemm<<<4, 256, 0, stream>>>(lin_w, w1, nullptr, Wc, 128);
  k_vecmat<<<1, 128, 0, stream>>>(lin_b, w1, bc);

  const int gbl = (N + 31) / 32;
  const int wbl = (N + 3) / 4;

  k_gemm_proj<false><<<gbl, 256, 0, stream>>>(x, Wc, as1, ad1, bc, hb, alpha_s, alpha_d, N);
  k_gat<<<wbl, 256, 0, stream>>>(hb, rowptr, esrc, alpha_s, alpha_d, b1, hb2, N, Etot);
  k_gemm_proj<true><<<gbl, 256, 0, stream>>>(hb2, w2, as2, ad2, nullptr, hb, alpha_s, alpha_d, N);
  k_gat<<<wbl, 256, 0, stream>>>(hb, rowptr, esrc, alpha_s, alpha_d, b2, hb2, N, Etot);
  k_poolout<<<G, 512, 0, stream>>>(hb2, gs, ge, ow, ob, out, N);
}

// Round 17
// 362.469 us; speedup vs baseline: 1.3564x; 1.0066x over previous
//
#include <hip/hip_runtime.h>
#include <hip/hip_bf16.h>

#define NEG_SLOPE 0.2f
#define BSHIFT 9                 // 512 nodes per bucket
#define MAXBUCK 128              // covers N up to 65536

static __device__ __forceinline__ float b2f(unsigned short u){
  return __uint_as_float(((unsigned int)u) << 16);
}
static __device__ __forceinline__ unsigned int pack_bf2(float a, float b){
  unsigned int ua = __float_as_uint(a);
  unsigned int ub = __float_as_uint(b);
  unsigned int ra = (ua + 0x7fffu + ((ua >> 16) & 1u)) >> 16;   // RNE
  unsigned int rb = (ub + 0x7fffu + ((ub >> 16) & 1u)) >> 16;
  return ra | (rb << 16);
}

// ---------------- init (deg zero) + graph bounds (batch sorted, boundary detect) ----------------
// gs/ge need no pre-init: every populated graph gets its boundary written; empty graphs
// read poison -> clamped to c=0 -> out=ob (deterministic).
__global__ __launch_bounds__(256) void k_init(const int* __restrict__ batch,
    int* deg, int* gs, int* ge, int n1, int n){
  int i = blockIdx.x * 256 + threadIdx.x;
  if(i < n1) deg[i] = 0;
  if(i < n){
    int g = batch[i];
    if(i == 0){
      gs[g] = 0;
    } else {
      int gp = batch[i - 1];
      if(gp != g){ gs[g] = i; ge[gp] = i; }
    }
    if(i == n - 1) ge[g] = n;
  }
}

// ---------------- prep: Wc = lin_w @ w1 (blocks 0-3), bc = lin_b @ w1 (block 4) ----------------
// GEMM body = round-11 inner loop (~100 VGPR, no spill).
// NOTE: 4-k float4-A blocking (round 12) spilled to scratch (256 VGPR, 2 GB traffic) — do not reintroduce.
// NOTE: atomicAdd pooling in k_gat (round 15) serialized 780-deep on 8192 addrs → 220 µs — do not reintroduce.
__global__ __launch_bounds__(256) void k_prep(const float* __restrict__ lin_w,
    const float* __restrict__ lin_b, const float* __restrict__ w1,
    float* __restrict__ Wc, float* __restrict__ bc){
  if(blockIdx.x == 4){
    int c = threadIdx.x;
    if(c < 128){
      float s = 0.f;
      for(int k = 0; k < 128; k++) s += lin_b[k] * w1[k * 128 + c];
      bc[c] = s;
    }
    return;
  }
  __shared__ float Wl[64 * 128];
  __shared__ float Al[32 * 128];
  const int t = threadIdx.x;
  const int row0 = blockIdx.x * 32;
  #pragma unroll
  for(int i = 0; i < 8; i++){
    int idx = t + i * 256;
    int r = idx >> 6, kk = idx & 63;
    ((float2*)Al)[r * 64 + kk] = ((const float2*)lin_w)[(size_t)(row0 + r) * 64 + kk];
  }
  const int c0 = (t & 31) * 4;
  const int rb = (t >> 5) * 4;
  float acc[4][4] = {};
  const float4* W4 = (const float4*)w1;
  #pragma unroll
  for(int h = 0; h < 2; h++){
    if(h) __syncthreads();
    #pragma unroll
    for(int i = 0; i < 8; i++) ((float4*)Wl)[t + i * 256] = W4[h * 2048 + t + i * 256];
    __syncthreads();
    const int kb = h * 64;
    #pragma unroll 8
    for(int k = 0; k < 64; k++){
      float4 wv = *(const float4*)&Wl[k * 128 + c0];
      float a0 = Al[(rb+0)*128 + kb + k];
      float a1 = Al[(rb+1)*128 + kb + k];
      float a2 = Al[(rb+2)*128 + kb + k];
      float a3 = Al[(rb+3)*128 + kb + k];
      acc[0][0] += a0*wv.x; acc[0][1] += a0*wv.y; acc[0][2] += a0*wv.z; acc[0][3] += a0*wv.w;
      acc[1][0] += a1*wv.x; acc[1][1] += a1*wv.y; acc[1][2] += a1*wv.z; acc[1][3] += a1*wv.w;
      acc[2][0] += a2*wv.x; acc[2][1] += a2*wv.y; acc[2][2] += a2*wv.z; acc[2][3] += a2*wv.w;
      acc[3][0] += a3*wv.x; acc[3][1] += a3*wv.y; acc[3][2] += a3*wv.z; acc[3][3] += a3*wv.w;
    }
  }
  #pragma unroll
  for(int j = 0; j < 4; j++){
    int rg = row0 + rb + j;
    *(float4*)&Wc[(size_t)rg * 128 + c0] =
      make_float4(acc[j][0], acc[j][1], acc[j][2], acc[j][3]);
  }
}

// ---------------- projection GEMM: bf16-packed out + fused alpha_s/alpha_d (+opt bias) ----------
// ABF: A is bf16-packed (uint per 2 features) — halves A-read traffic for layer 2.
template<bool ABF>
__global__ __launch_bounds__(256) void k_gemm_proj(const void* __restrict__ Av,
    const float* __restrict__ W, const float* __restrict__ a_src,
    const float* __restrict__ a_dst, const float* __restrict__ bias,
    unsigned int* __restrict__ hb,
    float* __restrict__ alpha_s, float* __restrict__ alpha_d, int nrows){
  __shared__ float Wl[64 * 128];
  __shared__ float Al[32 * 128];
  const int t = threadIdx.x;
  const int row0 = blockIdx.x * 32;
  #pragma unroll
  for(int i = 0; i < 8; i++){
    int idx = t + i * 256;
    int r = idx >> 6, kk = idx & 63;
    int rg = row0 + r; if(rg >= nrows) rg = nrows - 1;
    if(ABF){
      unsigned int v = ((const unsigned int*)Av)[(size_t)rg * 64 + kk];
      Al[r*128 + 2*kk]     = b2f((unsigned short)(v & 0xffffu));
      Al[r*128 + 2*kk + 1] = b2f((unsigned short)(v >> 16));
    } else {
      float2 v = ((const float2*)Av)[(size_t)rg * 64 + kk];
      Al[r*128 + 2*kk] = v.x; Al[r*128 + 2*kk + 1] = v.y;
    }
  }
  const int c0 = (t & 31) * 4;
  const int rb = (t >> 5) * 4;
  float acc[4][4] = {};
  const float4* W4 = (const float4*)W;
  #pragma unroll
  for(int h = 0; h < 2; h++){
    if(h) __syncthreads();
    #pragma unroll
    for(int i = 0; i < 8; i++) ((float4*)Wl)[t + i * 256] = W4[h * 2048 + t + i * 256];
    __syncthreads();
    const int kb = h * 64;
    #pragma unroll 8
    for(int k = 0; k < 64; k++){
      float4 wv = *(const float4*)&Wl[k * 128 + c0];
      float a0 = Al[(rb+0)*128 + kb + k];
      float a1 = Al[(rb+1)*128 + kb + k];
      float a2 = Al[(rb+2)*128 + kb + k];
      float a3 = Al[(rb+3)*128 + kb + k];
      acc[0][0] += a0*wv.x; acc[0][1] += a0*wv.y; acc[0][2] += a0*wv.z; acc[0][3] += a0*wv.w;
      acc[1][0] += a1*wv.x; acc[1][1] += a1*wv.y; acc[1][2] += a1*wv.z; acc[1][3] += a1*wv.w;
      acc[2][0] += a2*wv.x; acc[2][1] += a2*wv.y; acc[2][2] += a2*wv.z; acc[2][3] += a2*wv.w;
      acc[3][0] += a3*wv.x; acc[3][1] += a3*wv.y; acc[3][2] += a3*wv.z; acc[3][3] += a3*wv.w;
    }
  }
  if(bias){   // composite lin_in bias (must precede alpha dots)
    float b0 = bias[c0], b1 = bias[c0+1], b2v = bias[c0+2], b3 = bias[c0+3];
    #pragma unroll
    for(int j = 0; j < 4; j++){
      acc[j][0] += b0; acc[j][1] += b1; acc[j][2] += b2v; acc[j][3] += b3;
    }
  }
  float4 asv = *(const float4*)&a_src[c0];
  float4 adv = *(const float4*)&a_dst[c0];
  #pragma unroll
  for(int j = 0; j < 4; j++){
    int rg = row0 + rb + j;
    float s = acc[j][0]*asv.x + acc[j][1]*asv.y + acc[j][2]*asv.z + acc[j][3]*asv.w;
    float d = acc[j][0]*adv.x + acc[j][1]*adv.y + acc[j][2]*adv.z + acc[j][3]*adv.w;
    #pragma unroll
    for(int o = 16; o; o >>= 1){ s += __shfl_xor(s, o); d += __shfl_xor(d, o); }
    if(rg < nrows){
      if((t & 31) == 0){ alpha_s[rg] = s; alpha_d[rg] = d; }
      uint2 u = make_uint2(pack_bf2(acc[j][0], acc[j][1]), pack_bf2(acc[j][2], acc[j][3]));
      *(uint2*)&hb[(size_t)rg * 64 + (c0 >> 1)] = u;
    }
  }
}

// ---------------- CSR build: hist + 3-phase multi-block scan ----------------
__global__ __launch_bounds__(256) void k_hist(const int* __restrict__ ei, int* __restrict__ deg,
    int E, int Etot){
  int e = blockIdx.x * 256 + threadIdx.x;
  if(e >= Etot) return;
  int dst = (e < E) ? ei[E + e] : (e - E);
  atomicAdd(&deg[dst], 1);
}

__global__ __launch_bounds__(1024) void k_scanA(const int* __restrict__ deg,
    int* __restrict__ rowptr, int* __restrict__ bsum, int n){
  const int t = threadIdx.x;
  const int j0 = blockIdx.x * 4096 + t * 4;
  int v0 = 0, v1 = 0, v2 = 0, v3 = 0;
  if(j0 + 3 < n){
    int4 q = *(const int4*)&deg[j0];
    v0 = q.x; v1 = q.y; v2 = q.z; v3 = q.w;
  } else {
    if(j0     < n) v0 = deg[j0];
    if(j0 + 1 < n) v1 = deg[j0 + 1];
    if(j0 + 2 < n) v2 = deg[j0 + 2];
    if(j0 + 3 < n) v3 = deg[j0 + 3];
  }
  int p1 = v0 + v1, p2 = p1 + v2, tot = p2 + v3;
  const int lane = t & 63, wv = t >> 6;
  int incl = tot;
  #pragma unroll
  for(int off = 1; off < 64; off <<= 1){
    int x = __shfl_up(incl, off);
    if(lane >= off) incl += x;
  }
  __shared__ int wsum[16];
  if(lane == 63) wsum[wv] = incl;
  __syncthreads();
  if(wv == 0){
    int s = (lane < 16) ? wsum[lane] : 0;
    #pragma unroll
    for(int off = 1; off < 16; off <<= 1){
      int x = __shfl_up(s, off);
      if(lane >= off) s += x;
    }
    if(lane < 16) wsum[lane] = s;
  }
  __syncthreads();
  int woff = (wv > 0) ? wsum[wv - 1] : 0;
  int excl = woff + incl - tot;
  if(j0     < n) rowptr[j0 + 1] = excl + v0;
  if(j0 + 1 < n) rowptr[j0 + 2] = excl + p1;
  if(j0 + 2 < n) rowptr[j0 + 3] = excl + p2;
  if(j0 + 3 < n) rowptr[j0 + 4] = excl + tot;
  if(t == 1023) bsum[blockIdx.x] = woff + incl;
}

__global__ __launch_bounds__(64) void k_scanB(int* __restrict__ bsum, int nb){
  int lane = threadIdx.x;
  int v = (lane < nb) ? bsum[lane] : 0;
  int incl = v;
  #pragma unroll
  for(int off = 1; off < 64; off <<= 1){
    int x = __shfl_up(incl, off);
    if(lane >= off) incl += x;
  }
  if(lane < nb) bsum[lane] = incl - v;
}

// scanC + bucket-cursor init fused: bcur[b] = final rowptr[b<<BSHIFT]
__global__ __launch_bounds__(256) void k_scanC(int* __restrict__ rowptr,
    const int* __restrict__ bsum, int* __restrict__ bcur, int n){
  int idx = blockIdx.x * 256 + threadIdx.x;
  if(idx == 0){ rowptr[0] = 0; bcur[0] = 0; }
  int i = idx + 1;
  if(i <= n){
    int v = rowptr[i] + bsum[(i - 1) >> 12];
    rowptr[i] = v;
    if(i < n && (i & ((1 << BSHIFT) - 1)) == 0) bcur[i >> BSHIFT] = v;
  }
}

__global__ __launch_bounds__(256) void k_binA(const int* __restrict__ ei,
    int* __restrict__ bcur, uint2* __restrict__ staged, int E, int Etot){
  __shared__ int hist[MAXBUCK];
  __shared__ int scanb[MAXBUCK];
  __shared__ int delta[MAXBUCK];
  __shared__ uint2 buf[4096];     // 32 KB
  const int t = threadIdx.x;
  const int base = blockIdx.x * 4096;
  if(t < MAXBUCK) hist[t] = 0;
  __syncthreads();
  int myb[16], myi[16]; uint2 mye[16];
  #pragma unroll
  for(int k = 0; k < 16; k++){
    int e = base + t + k * 256;
    myb[k] = -1;
    if(e < Etot){
      int src, dst;
      if(e < E){ src = ei[e]; dst = ei[E + e]; }
      else { src = e - E; dst = src; }
      int b = dst >> BSHIFT;
      myi[k] = atomicAdd(&hist[b], 1);
      myb[k] = b;
      mye[k] = make_uint2((unsigned)src, (unsigned)dst);
    }
  }
  __syncthreads();
  if(t < MAXBUCK) scanb[t] = hist[t];
  __syncthreads();
  for(int off = 1; off < MAXBUCK; off <<= 1){
    int v = (t < MAXBUCK && t >= off) ? scanb[t - off] : 0;
    __syncthreads();
    if(t < MAXBUCK) scanb[t] += v;
    __syncthreads();
  }
  if(t < MAXBUCK){
    int excl = scanb[t] - hist[t];
    int gb = (hist[t] > 0) ? atomicAdd(&bcur[t], hist[t]) : 0;
    delta[t] = gb - excl;
    scanb[t] = excl;
  }
  __syncthreads();
  #pragma unroll
  for(int k = 0; k < 16; k++){
    if(myb[k] >= 0) buf[scanb[myb[k]] + myi[k]] = mye[k];
  }
  __syncthreads();
  int total = min(4096, Etot - base);
  for(int i = t; i < total; i += 256){
    uint2 ed = buf[i];
    int b = (int)(ed.y >> BSHIFT);
    staged[i + delta[b]] = ed;     // contiguous runs per bucket
  }
}

__global__ __launch_bounds__(256) void k_binB(const uint2* __restrict__ staged,
    const int* __restrict__ rowptr, int* __restrict__ esrc, int n){
  __shared__ int cur[1 << BSHIFT];
  const int b = blockIdx.x;
  const int n0 = b << BSHIFT;
  const int n1 = min(n, n0 + (1 << BSHIFT));
  const int t = threadIdx.x;
  for(int i = n0 + t; i < n1; i += 256) cur[i - n0] = rowptr[i];
  __syncthreads();
  const int lo = rowptr[n0];
  const int hi = rowptr[n1];
  for(int j = lo + t; j < hi; j += 256){
    uint2 ed = staged[j];
    int pos = atomicAdd(&cur[(int)ed.y - n0], 1);
    esrc[pos] = (int)ed.x;
  }
}

// ---------------- GAT: lane-parallel softmax + single gather walk, bf16 out ----------------
__global__ __launch_bounds__(256) void k_gat(const unsigned int* __restrict__ hb,
    const int* __restrict__ rowptr, const int* __restrict__ esrc,
    const float* __restrict__ a_s, const float* __restrict__ a_d,
    const float* __restrict__ bias, unsigned int* __restrict__ hb_out, int n, int Etot){
  int w = (blockIdx.x * 256 + threadIdx.x) >> 6;
  int lane = threadIdx.x & 63;
  if(w >= n) return;
  int s0 = rowptr[w], s1 = rowptr[w + 1];
  s0 = max(0, min(s0, Etot));
  s1 = max(s0, min(s1, Etot));
  const int deg = s1 - s0;
  const float adv = a_d[w];
  float2 acc0 = make_float2(0.f, 0.f), acc1 = make_float2(0.f, 0.f);
  float2 acc2 = make_float2(0.f, 0.f), acc3 = make_float2(0.f, 0.f);

  if(deg <= 64){
    int srcl = 0; float e = -1e30f;
    if(lane < deg){
      srcl = esrc[s0 + lane];
      srcl = ((unsigned)srcl < (unsigned)n) ? srcl : 0;
      e = a_s[srcl] + adv;
      e = e > 0.f ? e : NEG_SLOPE * e;
    }
    float m = e;
    #pragma unroll
    for(int o = 32; o; o >>= 1) m = fmaxf(m, __shfl_xor(m, o));
    float wgt = (lane < deg) ? __expf(e - m) : 0.f;
    float den = wgt;
    #pragma unroll
    for(int o = 32; o; o >>= 1) den += __shfl_xor(den, o);
    float winv = (den > 0.f) ? wgt / den : 0.f;
    int jj = 0;
    for(; jj + 8 <= deg; jj += 8){
      int   i0 = __shfl(srcl, jj),     i1 = __shfl(srcl, jj + 1);
      int   i2 = __shfl(srcl, jj + 2), i3 = __shfl(srcl, jj + 3);
      int   i4 = __shfl(srcl, jj + 4), i5 = __shfl(srcl, jj + 5);
      int   i6 = __shfl(srcl, jj + 6), i7 = __shfl(srcl, jj + 7);
      float w0 = __shfl(winv, jj),     w1 = __shfl(winv, jj + 1);
      float w2 = __shfl(winv, jj + 2), w3 = __shfl(winv, jj + 3);
      float w4 = __shfl(winv, jj + 4), w5 = __shfl(winv, jj + 5);
      float w6 = __shfl(winv, jj + 6), w7 = __shfl(winv, jj + 7);
      unsigned int u0 = hb[(((unsigned)i0) << 6) + lane];
      unsigned int u1 = hb[(((unsigned)i1) << 6) + lane];
      unsigned int u2 = hb[(((unsigned)i2) << 6) + lane];
      unsigned int u3 = hb[(((unsigned)i3) << 6) + lane];
      unsigned int u4 = hb[(((unsigned)i4) << 6) + lane];
      unsigned int u5 = hb[(((unsigned)i5) << 6) + lane];
      unsigned int u6 = hb[(((unsigned)i6) << 6) + lane];
      unsigned int u7 = hb[(((unsigned)i7) << 6) + lane];
      acc0.x += w0 * b2f((unsigned short)(u0 & 0xffffu)); acc0.y += w0 * b2f((unsigned short)(u0 >> 16));
      acc1.x += w1 * b2f((unsigned short)(u1 & 0xffffu)); acc1.y += w1 * b2f((unsigned short)(u1 >> 16));
      acc2.x += w2 * b2f((unsigned short)(u2 & 0xffffu)); acc2.y += w2 * b2f((unsigned short)(u2 >> 16));
      acc3.x += w3 * b2f((unsigned short)(u3 & 0xffffu)); acc3.y += w3 * b2f((unsigned short)(u3 >> 16));
      acc0.x += w4 * b2f((unsigned short)(u4 & 0xffffu)); acc0.y += w4 * b2f((unsigned short)(u4 >> 16));
      acc1.x += w5 * b2f((unsigned short)(u5 & 0xffffu)); acc1.y += w5 * b2f((unsigned short)(u5 >> 16));
      acc2.x += w6 * b2f((unsigned short)(u6 & 0xffffu)); acc2.y += w6 * b2f((unsigned short)(u6 >> 16));
      acc3.x += w7 * b2f((unsigned short)(u7 & 0xffffu)); acc3.y += w7 * b2f((unsigned short)(u7 >> 16));
    }
    for(; jj < deg; jj++){
      int   ci = __shfl(srcl, jj);
      float wv = __shfl(winv, jj);
      unsigned int u = hb[(((unsigned)ci) << 6) + lane];
      acc0.x += wv * b2f((unsigned short)(u & 0xffffu));
      acc0.y += wv * b2f((unsigned short)(u >> 16));
    }
  } else {
    float m = -1e30f;
    for(int j = s0 + lane; j < s1; j += 64){
      int s = esrc[j]; s = ((unsigned)s < (unsigned)n) ? s : 0;
      float e = a_s[s] + adv;
      e = e > 0.f ? e : NEG_SLOPE * e;
      m = fmaxf(m, e);
    }
    #pragma unroll
    for(int o = 32; o; o >>= 1) m = fmaxf(m, __shfl_xor(m, o));
    float den = 0.f;
    for(int j = s0 + lane; j < s1; j += 64){
      int s = esrc[j]; s = ((unsigned)s < (unsigned)n) ? s : 0;
      float e = a_s[s] + adv;
      e = e > 0.f ? e : NEG_SLOPE * e;
      den += __expf(e - m);
    }
    #pragma unroll
    for(int o = 32; o; o >>= 1) den += __shfl_xor(den, o);
    float inv = (den > 0.f) ? 1.f / den : 0.f;
    for(int j = s0; j < s1; j++){
      int s = esrc[j]; s = ((unsigned)s < (unsigned)n) ? s : 0;
      float e = a_s[s] + adv;
      e = e > 0.f ? e : NEG_SLOPE * e;
      float wv = __expf(e - m) * inv;
      unsigned int u = hb[(((unsigned)s) << 6) + lane];
      acc0.x += wv * b2f((unsigned short)(u & 0xffffu));
      acc0.y += wv * b2f((unsigned short)(u >> 16));
    }
  }
  float2 bl = ((const float2*)bias)[lane];
  float ox = (acc0.x + acc1.x) + (acc2.x + acc3.x) + bl.x;
  float oy = (acc0.y + acc1.y) + (acc2.y + acc3.y) + bl.y;
  ox = 0.5f * (ox + fabsf(ox));   // NaN-transparent relu
  oy = 0.5f * (oy + fabsf(oy));
  hb_out[(size_t)w * 64 + lane] = pack_bf2(ox, oy);
}

// ---------------- mean-pool (bf16 h) + fused head ----------------
__global__ __launch_bounds__(512) void k_poolout(const unsigned int* __restrict__ h2,
    const int* __restrict__ gs, const int* __restrict__ ge,
    const float* __restrict__ out_w, const float* __restrict__ out_b,
    float* __restrict__ out, int n){
  const int g = blockIdx.x;
  const int t = threadIdx.x;
  const int f2 = t & 63;          // packed-uint column (features 2*f2, 2*f2+1)
  const int rr = t >> 6;          // row phase 0..7
  int s = gs[g], e = ge[g];
  s = max(0, min(s, n)); e = max(s, min(e, n));
  float sx = 0.f, sy = 0.f;
  for(int i = s + rr; i < e; i += 8){
    unsigned int u = h2[(size_t)i * 64 + f2];
    sx += b2f((unsigned short)(u & 0xffffu));
    sy += b2f((unsigned short)(u >> 16));
  }
  __shared__ float part[8 * 128];
  part[rr * 128 + 2 * f2]     = sx;
  part[rr * 128 + 2 * f2 + 1] = sy;
  __syncthreads();
  __shared__ float red[2];
  if(t < 128){
    float tot = 0.f;
    #pragma unroll
    for(int r = 0; r < 8; r++) tot += part[r * 128 + t];
    int c = e - s;
    float invc = (c > 0) ? 1.f / (float)c : 0.f;
    float v = tot * invc * out_w[t];
    #pragma unroll
    for(int o = 32; o; o >>= 1) v += __shfl_xor(v, o);
    if((t & 63) == 0) red[t >> 6] = v;
  }
  __syncthreads();
  if(t == 0) out[g] = red[0] + red[1] + out_b[0];
}

extern "C" void kernel_launch(void* const* d_in, const int* in_sizes, int n_in,
                              void* d_out, int out_size, void* d_ws, size_t ws_size,
                              hipStream_t stream){
  const float* x     = (const float*)d_in[0];
  const int*   ei    = (const int*)d_in[1];
  const int*   batch = (const int*)d_in[2];
  const float* lin_w = (const float*)d_in[3];
  const float* lin_b = (const float*)d_in[4];
  const float* w1    = (const float*)d_in[5];
  const float* as1   = (const float*)d_in[6];
  const float* ad1   = (const float*)d_in[7];
  const float* b1    = (const float*)d_in[8];
  const float* w2    = (const float*)d_in[9];
  const float* as2   = (const float*)d_in[10];
  const float* ad2   = (const float*)d_in[11];
  const float* b2    = (const float*)d_in[12];
  const float* ow    = (const float*)d_in[13];
  const float* ob    = (const float*)d_in[14];
  float* out = (float*)d_out;

  const int N = in_sizes[0] / 128;
  const int E = in_sizes[1] / 2;
  const int Etot = E + N;
  const int G = out_size;
  const int nbuck = (N + (1 << BSHIFT) - 1) >> BSHIFT;
  const int nsb = (N + 4095) / 4096;     // scan blocks (<=64)

  char* p = (char*)d_ws;
  int*   deg     = (int*)p;   p += (size_t)(N + 1) * 4;
  int*   rowptr  = (int*)p;   p += (size_t)(N + 1) * 4;
  int*   bcur    = (int*)p;   p += (size_t)MAXBUCK * 4;
  int*   bsum    = (int*)p;   p += (size_t)64 * 4;
  int*   gs      = (int*)p;   p += (size_t)G * 4;
  int*   ge      = (int*)p;   p += (size_t)G * 4;
  float* alpha_s = (float*)p; p += (size_t)N * 4;
  float* alpha_d = (float*)p; p += (size_t)N * 4;
  float* Wc      = (float*)p; p += (size_t)128 * 128 * 4;  // Win@W1 composite
  float* bc      = (float*)p; p += (size_t)128 * 4;        // b_in@W1
  int*   esrc    = (int*)p;   p += (size_t)Etot * 4;
  uint2* staged  = (uint2*)p; p += (size_t)Etot * 8;
  unsigned int* hb  = (unsigned int*)p; p += (size_t)N * 64 * 4;  // projection, bf16-packed
  unsigned int* hb2 = (unsigned int*)p; p += (size_t)N * 64 * 4;  // h1 / h2, bf16-packed

  const int ebl = (Etot + 255) / 256;
  k_init<<<(N + 256) / 256, 256, 0, stream>>>(batch, deg, gs, ge, N + 1, N);
  k_hist<<<ebl, 256, 0, stream>>>(ei, deg, E, Etot);
  k_scanA<<<nsb, 1024, 0, stream>>>(deg, rowptr, bsum, N);
  k_scanB<<<1, 64, 0, stream>>>(bsum, nsb);
  k_scanC<<<(N + 255) / 256, 256, 0, stream>>>(rowptr, bsum, bcur, N);
  k_binA<<<(Etot + 4095) / 4096, 256, 0, stream>>>(ei, bcur, staged, E, Etot);
  k_binB<<<nbuck, 256, 0, stream>>>(staged, rowptr, esrc, N);

  // composite: proj1 = x @ (Win@W1) + b_in@W1  (no nonlinearity between lin_in and proj1)
  k_prep<<<5, 256, 0, stream>>>(lin_w, lin_b, w1, Wc, bc);

  const int gbl = (N + 31) / 32;
  const int wbl = (N + 3) / 4;

  k_gemm_proj<false><<<gbl, 256, 0, stream>>>(x, Wc, as1, ad1, bc, hb, alpha_s, alpha_d, N);
  k_gat<<<wbl, 256, 0, stream>>>(hb, rowptr, esrc, alpha_s, alpha_d, b1, hb2, N, Etot);
  k_gemm_proj<true><<<gbl, 256, 0, stream>>>(hb2, w2, as2, ad2, nullptr, hb, alpha_s, alpha_d, N);
  k_gat<<<wbl, 256, 0, stream>>>(hb, rowptr, esrc, alpha_s, alpha_d, b2, hb2, N, Etot);
  k_poolout<<<G, 512, 0, stream>>>(hb2, gs, ge, ow, ob, out, N);
}

// Round 18
// 336.548 us; speedup vs baseline: 1.4609x; 1.0770x over previous
//
#include <hip/hip_runtime.h>
#include <hip/hip_bf16.h>

#define NEG_SLOPE 0.2f
#define BSHIFT 9                 // 512 nodes per bucket
#define MAXBUCK 128              // covers N up to 65536
#define LDA 136                  // padded LDS row stride (bf16 elems): 272 B -> 16B-aligned rows, 2-way-free banks

typedef __attribute__((ext_vector_type(8))) short bfrag;   // 8 bf16 (4 VGPRs)
typedef __attribute__((ext_vector_type(4))) float ffrag;   // 4 f32 acc

static __device__ __forceinline__ float b2f(unsigned short u){
  return __uint_as_float(((unsigned int)u) << 16);
}
static __device__ __forceinline__ unsigned short f2b16(float f){
  unsigned int u = __float_as_uint(f);
  return (unsigned short)((u + 0x7fffu + ((u >> 16) & 1u)) >> 16);   // RNE
}
static __device__ __forceinline__ unsigned int pack_bf2(float a, float b){
  return (unsigned int)f2b16(a) | ((unsigned int)f2b16(b) << 16);
}

// ---------------- init (deg zero) + graph bounds (batch sorted, boundary detect) ----------------
__global__ __launch_bounds__(256) void k_init(const int* __restrict__ batch,
    int* deg, int* gs, int* ge, int n1, int n){
  int i = blockIdx.x * 256 + threadIdx.x;
  if(i < n1) deg[i] = 0;
  if(i < n){
    int g = batch[i];
    if(i == 0){
      gs[g] = 0;
    } else {
      int gp = batch[i - 1];
      if(gp != g){ gs[g] = i; ge[gp] = i; }
    }
    if(i == n - 1) ge[g] = n;
  }
}

// ---------------- prep: Wc = lin_w @ w1 (blocks 0-3), bc = lin_b @ w1 (block 4), f32 VALU ----
// NOTE: 4-k float4-A blocking (round 12) spilled to scratch — do not reintroduce.
// NOTE: atomicAdd pooling in k_gat (round 15) serialized 780-deep — do not reintroduce.
__global__ __launch_bounds__(256) void k_prep(const float* __restrict__ lin_w,
    const float* __restrict__ lin_b, const float* __restrict__ w1,
    float* __restrict__ Wc, float* __restrict__ bc){
  if(blockIdx.x == 4){
    int c = threadIdx.x;
    if(c < 128){
      float s = 0.f;
      for(int k = 0; k < 128; k++) s += lin_b[k] * w1[k * 128 + c];
      bc[c] = s;
    }
    return;
  }
  __shared__ float Wl[64 * 128];
  __shared__ float Al[32 * 128];
  const int t = threadIdx.x;
  const int row0 = blockIdx.x * 32;
  #pragma unroll
  for(int i = 0; i < 8; i++){
    int idx = t + i * 256;
    int r = idx >> 6, kk = idx & 63;
    ((float2*)Al)[r * 64 + kk] = ((const float2*)lin_w)[(size_t)(row0 + r) * 64 + kk];
  }
  const int c0 = (t & 31) * 4;
  const int rb = (t >> 5) * 4;
  float acc[4][4] = {};
  const float4* W4 = (const float4*)w1;
  #pragma unroll
  for(int h = 0; h < 2; h++){
    if(h) __syncthreads();
    #pragma unroll
    for(int i = 0; i < 8; i++) ((float4*)Wl)[t + i * 256] = W4[h * 2048 + t + i * 256];
    __syncthreads();
    const int kb = h * 64;
    #pragma unroll 8
    for(int k = 0; k < 64; k++){
      float4 wv = *(const float4*)&Wl[k * 128 + c0];
      float a0 = Al[(rb+0)*128 + kb + k];
      float a1 = Al[(rb+1)*128 + kb + k];
      float a2 = Al[(rb+2)*128 + kb + k];
      float a3 = Al[(rb+3)*128 + kb + k];
      acc[0][0] += a0*wv.x; acc[0][1] += a0*wv.y; acc[0][2] += a0*wv.z; acc[0][3] += a0*wv.w;
      acc[1][0] += a1*wv.x; acc[1][1] += a1*wv.y; acc[1][2] += a1*wv.z; acc[1][3] += a1*wv.w;
      acc[2][0] += a2*wv.x; acc[2][1] += a2*wv.y; acc[2][2] += a2*wv.z; acc[2][3] += a2*wv.w;
      acc[3][0] += a3*wv.x; acc[3][1] += a3*wv.y; acc[3][2] += a3*wv.z; acc[3][3] += a3*wv.w;
    }
  }
  #pragma unroll
  for(int j = 0; j < 4; j++){
    int rg = row0 + rb + j;
    *(float4*)&Wc[(size_t)rg * 128 + c0] =
      make_float4(acc[j][0], acc[j][1], acc[j][2], acc[j][3]);
  }
}

// ---------------- projection GEMM (MFMA bf16): bf16-packed out + fused alpha (+opt bias) ------
// Block = 256 thr (4 waves), tile 64 rows x 128 cols. Per wave: 16 rows, 8 col-tiles of
// 16x16, K=128 as 4 steps of v_mfma_f32_16x16x32_bf16 (f32 accumulate).
// Layouts (HW-verified): A[m=lane&15][k=quad*8+j]; B[k=quad*8+j][n=lane&15] (W transposed
// in LDS); C/D col=lane&15, row=quad*4+reg.
template<bool ABF>
__global__ __launch_bounds__(256) void k_gemm_proj(const void* __restrict__ Av,
    const float* __restrict__ W, const float* __restrict__ a_src,
    const float* __restrict__ a_dst, const float* __restrict__ bias,
    unsigned int* __restrict__ hb,
    float* __restrict__ alpha_s, float* __restrict__ alpha_d, int nrows){
  __shared__ unsigned short Wt[128 * LDA];   // 34816 B: Wt[n][k], bf16
  __shared__ unsigned short Aw[64 * LDA];    // 17408 B: A tile, bf16 (reused as out-stage)
  const int t = threadIdx.x;
  const int row0 = blockIdx.x * 64;
  // stage W transposed to bf16
  {
    const float4* W4 = (const float4*)W;     // W[k][n] row-major, 4096 float4
    #pragma unroll
    for(int i = 0; i < 16; i++){
      int idx = t + i * 256;
      int k = idx >> 5, n0 = (idx & 31) * 4;
      float4 w = W4[idx];
      Wt[(n0+0) * LDA + k] = f2b16(w.x);
      Wt[(n0+1) * LDA + k] = f2b16(w.y);
      Wt[(n0+2) * LDA + k] = f2b16(w.z);
      Wt[(n0+3) * LDA + k] = f2b16(w.w);
    }
  }
  // stage A to bf16
  if(ABF){
    #pragma unroll
    for(int i = 0; i < 8; i++){
      int idx = t + i * 256;                 // 0..2047, 32 uint2 per row
      int r = idx >> 5;
      int rg = row0 + r; if(rg >= nrows) rg = nrows - 1;
      uint2 v = ((const uint2*)Av)[(size_t)rg * 32 + (idx & 31)];
      unsigned int* dst = (unsigned int*)&Aw[r * LDA];
      dst[(idx & 31) * 2]     = v.x;
      dst[(idx & 31) * 2 + 1] = v.y;
    }
  } else {
    #pragma unroll
    for(int i = 0; i < 16; i++){
      int idx = t + i * 256;                 // 0..4095, 64 float2 per row
      int r = idx >> 6, c2 = idx & 63;
      int rg = row0 + r; if(rg >= nrows) rg = nrows - 1;
      float2 v = ((const float2*)Av)[(size_t)rg * 64 + c2];
      ((unsigned int*)&Aw[r * LDA])[c2] = pack_bf2(v.x, v.y);
    }
  }
  __syncthreads();

  const int lane = t & 63;
  const int wv = t >> 6;
  const int quad = lane >> 4, l = lane & 15;
  const int rw = wv * 16;
  bfrag a[4];
  #pragma unroll
  for(int kk = 0; kk < 4; kk++)
    a[kk] = *(const bfrag*)&Aw[(rw + l) * LDA + kk * 32 + quad * 8];
  ffrag acc[8];
  #pragma unroll
  for(int c = 0; c < 8; c++){
    ffrag z; z[0] = 0.f; z[1] = 0.f; z[2] = 0.f; z[3] = 0.f;
    acc[c] = z;
    #pragma unroll
    for(int kk = 0; kk < 4; kk++){
      bfrag b = *(const bfrag*)&Wt[(c * 16 + l) * LDA + kk * 32 + quad * 8];
      acc[c] = __builtin_amdgcn_mfma_f32_16x16x32_bf16(a[kk], b, acc[c], 0, 0, 0);
    }
  }
  // epilogue: bias (pre-alpha), alpha dots, pack
  float sdot[4] = {0.f,0.f,0.f,0.f}, ddot[4] = {0.f,0.f,0.f,0.f};
  #pragma unroll
  for(int c = 0; c < 8; c++){
    int col = c * 16 + l;
    float bv = bias ? bias[col] : 0.f;
    float as_ = a_src[col], ad_ = a_dst[col];
    #pragma unroll
    for(int r = 0; r < 4; r++){
      float v = acc[c][r] + bv;
      acc[c][r] = v;
      sdot[r] += v * as_;
      ddot[r] += v * ad_;
    }
  }
  #pragma unroll
  for(int r = 0; r < 4; r++){
    #pragma unroll
    for(int o = 1; o < 16; o <<= 1){
      sdot[r] += __shfl_xor(sdot[r], o);
      ddot[r] += __shfl_xor(ddot[r], o);
    }
  }
  if(l == 0){
    #pragma unroll
    for(int r = 0; r < 4; r++){
      int R = row0 + rw + quad * 4 + r;
      if(R < nrows){ alpha_s[R] = sdot[r]; alpha_d[R] = ddot[r]; }
    }
  }
  __syncthreads();                            // everyone done reading Aw/Wt
  unsigned short* ost = (unsigned short*)Aw;  // 64 rows x 128 bf16 (unpadded)
  #pragma unroll
  for(int c = 0; c < 8; c++){
    int col = c * 16 + l;
    #pragma unroll
    for(int r = 0; r < 4; r++)
      ost[(rw + quad * 4 + r) * 128 + col] = f2b16(acc[c][r]);
  }
  __syncthreads();
  #pragma unroll
  for(int i = 0; i < 4; i++){
    int idx = t + i * 256;                    // 0..1023 uint4 units, 16 per row
    int r = idx >> 4;
    int rg = row0 + r;
    if(rg < nrows){
      uint4 v = ((const uint4*)ost)[idx];
      ((uint4*)&hb[(size_t)rg * 64])[idx & 15] = v;
    }
  }
}

// ---------------- CSR build: hist + 3-phase multi-block scan ----------------
__global__ __launch_bounds__(256) void k_hist(const int* __restrict__ ei, int* __restrict__ deg,
    int E, int Etot){
  int e = blockIdx.x * 256 + threadIdx.x;
  if(e >= Etot) return;
  int dst = (e < E) ? ei[E + e] : (e - E);
  atomicAdd(&deg[dst], 1);
}

__global__ __launch_bounds__(1024) void k_scanA(const int* __restrict__ deg,
    int* __restrict__ rowptr, int* __restrict__ bsum, int n){
  const int t = threadIdx.x;
  const int j0 = blockIdx.x * 4096 + t * 4;
  int v0 = 0, v1 = 0, v2 = 0, v3 = 0;
  if(j0 + 3 < n){
    int4 q = *(const int4*)&deg[j0];
    v0 = q.x; v1 = q.y; v2 = q.z; v3 = q.w;
  } else {
    if(j0     < n) v0 = deg[j0];
    if(j0 + 1 < n) v1 = deg[j0 + 1];
    if(j0 + 2 < n) v2 = deg[j0 + 2];
    if(j0 + 3 < n) v3 = deg[j0 + 3];
  }
  int p1 = v0 + v1, p2 = p1 + v2, tot = p2 + v3;
  const int lane = t & 63, wv = t >> 6;
  int incl = tot;
  #pragma unroll
  for(int off = 1; off < 64; off <<= 1){
    int x = __shfl_up(incl, off);
    if(lane >= off) incl += x;
  }
  __shared__ int wsum[16];
  if(lane == 63) wsum[wv] = incl;
  __syncthreads();
  if(wv == 0){
    int s = (lane < 16) ? wsum[lane] : 0;
    #pragma unroll
    for(int off = 1; off < 16; off <<= 1){
      int x = __shfl_up(s, off);
      if(lane >= off) s += x;
    }
    if(lane < 16) wsum[lane] = s;
  }
  __syncthreads();
  int woff = (wv > 0) ? wsum[wv - 1] : 0;
  int excl = woff + incl - tot;
  if(j0     < n) rowptr[j0 + 1] = excl + v0;
  if(j0 + 1 < n) rowptr[j0 + 2] = excl + p1;
  if(j0 + 2 < n) rowptr[j0 + 3] = excl + p2;
  if(j0 + 3 < n) rowptr[j0 + 4] = excl + tot;
  if(t == 1023) bsum[blockIdx.x] = woff + incl;
}

__global__ __launch_bounds__(64) void k_scanB(int* __restrict__ bsum, int nb){
  int lane = threadIdx.x;
  int v = (lane < nb) ? bsum[lane] : 0;
  int incl = v;
  #pragma unroll
  for(int off = 1; off < 64; off <<= 1){
    int x = __shfl_up(incl, off);
    if(lane >= off) incl += x;
  }
  if(lane < nb) bsum[lane] = incl - v;
}

__global__ __launch_bounds__(256) void k_scanC(int* __restrict__ rowptr,
    const int* __restrict__ bsum, int* __restrict__ bcur, int n){
  int idx = blockIdx.x * 256 + threadIdx.x;
  if(idx == 0){ rowptr[0] = 0; bcur[0] = 0; }
  int i = idx + 1;
  if(i <= n){
    int v = rowptr[i] + bsum[(i - 1) >> 12];
    rowptr[i] = v;
    if(i < n && (i & ((1 << BSHIFT) - 1)) == 0) bcur[i >> BSHIFT] = v;
  }
}

__global__ __launch_bounds__(256) void k_binA(const int* __restrict__ ei,
    int* __restrict__ bcur, uint2* __restrict__ staged, int E, int Etot){
  __shared__ int hist[MAXBUCK];
  __shared__ int scanb[MAXBUCK];
  __shared__ int delta[MAXBUCK];
  __shared__ uint2 buf[4096];     // 32 KB
  const int t = threadIdx.x;
  const int base = blockIdx.x * 4096;
  if(t < MAXBUCK) hist[t] = 0;
  __syncthreads();
  int myb[16], myi[16]; uint2 mye[16];
  #pragma unroll
  for(int k = 0; k < 16; k++){
    int e = base + t + k * 256;
    myb[k] = -1;
    if(e < Etot){
      int src, dst;
      if(e < E){ src = ei[e]; dst = ei[E + e]; }
      else { src = e - E; dst = src; }
      int b = dst >> BSHIFT;
      myi[k] = atomicAdd(&hist[b], 1);
      myb[k] = b;
      mye[k] = make_uint2((unsigned)src, (unsigned)dst);
    }
  }
  __syncthreads();
  if(t < MAXBUCK) scanb[t] = hist[t];
  __syncthreads();
  for(int off = 1; off < MAXBUCK; off <<= 1){
    int v = (t < MAXBUCK && t >= off) ? scanb[t - off] : 0;
    __syncthreads();
    if(t < MAXBUCK) scanb[t] += v;
    __syncthreads();
  }
  if(t < MAXBUCK){
    int excl = scanb[t] - hist[t];
    int gb = (hist[t] > 0) ? atomicAdd(&bcur[t], hist[t]) : 0;
    delta[t] = gb - excl;
    scanb[t] = excl;
  }
  __syncthreads();
  #pragma unroll
  for(int k = 0; k < 16; k++){
    if(myb[k] >= 0) buf[scanb[myb[k]] + myi[k]] = mye[k];
  }
  __syncthreads();
  int total = min(4096, Etot - base);
  for(int i = t; i < total; i += 256){
    uint2 ed = buf[i];
    int b = (int)(ed.y >> BSHIFT);
    staged[i + delta[b]] = ed;     // contiguous runs per bucket
  }
}

__global__ __launch_bounds__(256) void k_binB(const uint2* __restrict__ staged,
    const int* __restrict__ rowptr, int* __restrict__ esrc, int n){
  __shared__ int cur[1 << BSHIFT];
  const int b = blockIdx.x;
  const int n0 = b << BSHIFT;
  const int n1 = min(n, n0 + (1 << BSHIFT));
  const int t = threadIdx.x;
  for(int i = n0 + t; i < n1; i += 256) cur[i - n0] = rowptr[i];
  __syncthreads();
  const int lo = rowptr[n0];
  const int hi = rowptr[n1];
  for(int j = lo + t; j < hi; j += 256){
    uint2 ed = staged[j];
    int pos = atomicAdd(&cur[(int)ed.y - n0], 1);
    esrc[pos] = (int)ed.x;
  }
}

// ---------------- GAT: lane-parallel softmax + single gather walk, bf16 out ----------------
__global__ __launch_bounds__(256) void k_gat(const unsigned int* __restrict__ hb,
    const int* __restrict__ rowptr, const int* __restrict__ esrc,
    const float* __restrict__ a_s, const float* __restrict__ a_d,
    const float* __restrict__ bias, unsigned int* __restrict__ hb_out, int n, int Etot){
  int w = (blockIdx.x * 256 + threadIdx.x) >> 6;
  int lane = threadIdx.x & 63;
  if(w >= n) return;
  int s0 = rowptr[w], s1 = rowptr[w + 1];
  s0 = max(0, min(s0, Etot));
  s1 = max(s0, min(s1, Etot));
  const int deg = s1 - s0;
  const float adv = a_d[w];
  float2 acc0 = make_float2(0.f, 0.f), acc1 = make_float2(0.f, 0.f);
  float2 acc2 = make_float2(0.f, 0.f), acc3 = make_float2(0.f, 0.f);

  if(deg <= 64){
    int srcl = 0; float e = -1e30f;
    if(lane < deg){
      srcl = esrc[s0 + lane];
      srcl = ((unsigned)srcl < (unsigned)n) ? srcl : 0;
      e = a_s[srcl] + adv;
      e = e > 0.f ? e : NEG_SLOPE * e;
    }
    float m = e;
    #pragma unroll
    for(int o = 32; o; o >>= 1) m = fmaxf(m, __shfl_xor(m, o));
    float wgt = (lane < deg) ? __expf(e - m) : 0.f;
    float den = wgt;
    #pragma unroll
    for(int o = 32; o; o >>= 1) den += __shfl_xor(den, o);
    float winv = (den > 0.f) ? wgt / den : 0.f;
    int jj = 0;
    for(; jj + 8 <= deg; jj += 8){
      int   i0 = __shfl(srcl, jj),     i1 = __shfl(srcl, jj + 1);
      int   i2 = __shfl(srcl, jj + 2), i3 = __shfl(srcl, jj + 3);
      int   i4 = __shfl(srcl, jj + 4), i5 = __shfl(srcl, jj + 5);
      int   i6 = __shfl(srcl, jj + 6), i7 = __shfl(srcl, jj + 7);
      float w0 = __shfl(winv, jj),     w1 = __shfl(winv, jj + 1);
      float w2 = __shfl(winv, jj + 2), w3 = __shfl(winv, jj + 3);
      float w4 = __shfl(winv, jj + 4), w5 = __shfl(winv, jj + 5);
      float w6 = __shfl(winv, jj + 6), w7 = __shfl(winv, jj + 7);
      unsigned int u0 = hb[(((unsigned)i0) << 6) + lane];
      unsigned int u1 = hb[(((unsigned)i1) << 6) + lane];
      unsigned int u2 = hb[(((unsigned)i2) << 6) + lane];
      unsigned int u3 = hb[(((unsigned)i3) << 6) + lane];
      unsigned int u4 = hb[(((unsigned)i4) << 6) + lane];
      unsigned int u5 = hb[(((unsigned)i5) << 6) + lane];
      unsigned int u6 = hb[(((unsigned)i6) << 6) + lane];
      unsigned int u7 = hb[(((unsigned)i7) << 6) + lane];
      acc0.x += w0 * b2f((unsigned short)(u0 & 0xffffu)); acc0.y += w0 * b2f((unsigned short)(u0 >> 16));
      acc1.x += w1 * b2f((unsigned short)(u1 & 0xffffu)); acc1.y += w1 * b2f((unsigned short)(u1 >> 16));
      acc2.x += w2 * b2f((unsigned short)(u2 & 0xffffu)); acc2.y += w2 * b2f((unsigned short)(u2 >> 16));
      acc3.x += w3 * b2f((unsigned short)(u3 & 0xffffu)); acc3.y += w3 * b2f((unsigned short)(u3 >> 16));
      acc0.x += w4 * b2f((unsigned short)(u4 & 0xffffu)); acc0.y += w4 * b2f((unsigned short)(u4 >> 16));
      acc1.x += w5 * b2f((unsigned short)(u5 & 0xffffu)); acc1.y += w5 * b2f((unsigned short)(u5 >> 16));
      acc2.x += w6 * b2f((unsigned short)(u6 & 0xffffu)); acc2.y += w6 * b2f((unsigned short)(u6 >> 16));
      acc3.x += w7 * b2f((unsigned short)(u7 & 0xffffu)); acc3.y += w7 * b2f((unsigned short)(u7 >> 16));
    }
    for(; jj < deg; jj++){
      int   ci = __shfl(srcl, jj);
      float wv = __shfl(winv, jj);
      unsigned int u = hb[(((unsigned)ci) << 6) + lane];
      acc0.x += wv * b2f((unsigned short)(u & 0xffffu));
      acc0.y += wv * b2f((unsigned short)(u >> 16));
    }
  } else {
    float m = -1e30f;
    for(int j = s0 + lane; j < s1; j += 64){
      int s = esrc[j]; s = ((unsigned)s < (unsigned)n) ? s : 0;
      float e = a_s[s] + adv;
      e = e > 0.f ? e : NEG_SLOPE * e;
      m = fmaxf(m, e);
    }
    #pragma unroll
    for(int o = 32; o; o >>= 1) m = fmaxf(m, __shfl_xor(m, o));
    float den = 0.f;
    for(int j = s0 + lane; j < s1; j += 64){
      int s = esrc[j]; s = ((unsigned)s < (unsigned)n) ? s : 0;
      float e = a_s[s] + adv;
      e = e > 0.f ? e : NEG_SLOPE * e;
      den += __expf(e - m);
    }
    #pragma unroll
    for(int o = 32; o; o >>= 1) den += __shfl_xor(den, o);
    float inv = (den > 0.f) ? 1.f / den : 0.f;
    for(int j = s0; j < s1; j++){
      int s = esrc[j]; s = ((unsigned)s < (unsigned)n) ? s : 0;
      float e = a_s[s] + adv;
      e = e > 0.f ? e : NEG_SLOPE * e;
      float wv = __expf(e - m) * inv;
      unsigned int u = hb[(((unsigned)s) << 6) + lane];
      acc0.x += wv * b2f((unsigned short)(u & 0xffffu));
      acc0.y += wv * b2f((unsigned short)(u >> 16));
    }
  }
  float2 bl = ((const float2*)bias)[lane];
  float ox = (acc0.x + acc1.x) + (acc2.x + acc3.x) + bl.x;
  float oy = (acc0.y + acc1.y) + (acc2.y + acc3.y) + bl.y;
  ox = 0.5f * (ox + fabsf(ox));   // NaN-transparent relu
  oy = 0.5f * (oy + fabsf(oy));
  hb_out[(size_t)w * 64 + lane] = pack_bf2(ox, oy);
}

// ---------------- mean-pool (bf16 h) + fused head ----------------
__global__ __launch_bounds__(512) void k_poolout(const unsigned int* __restrict__ h2,
    const int* __restrict__ gs, const int* __restrict__ ge,
    const float* __restrict__ out_w, const float* __restrict__ out_b,
    float* __restrict__ out, int n){
  const int g = blockIdx.x;
  const int t = threadIdx.x;
  const int f2 = t & 63;          // packed-uint column (features 2*f2, 2*f2+1)
  const int rr = t >> 6;          // row phase 0..7
  int s = gs[g], e = ge[g];
  s = max(0, min(s, n)); e = max(s, min(e, n));
  float sx = 0.f, sy = 0.f;
  for(int i = s + rr; i < e; i += 8){
    unsigned int u = h2[(size_t)i * 64 + f2];
    sx += b2f((unsigned short)(u & 0xffffu));
    sy += b2f((unsigned short)(u >> 16));
  }
  __shared__ float part[8 * 128];
  part[rr * 128 + 2 * f2]     = sx;
  part[rr * 128 + 2 * f2 + 1] = sy;
  __syncthreads();
  __shared__ float red[2];
  if(t < 128){
    float tot = 0.f;
    #pragma unroll
    for(int r = 0; r < 8; r++) tot += part[r * 128 + t];
    int c = e - s;
    float invc = (c > 0) ? 1.f / (float)c : 0.f;
    float v = tot * invc * out_w[t];
    #pragma unroll
    for(int o = 32; o; o >>= 1) v += __shfl_xor(v, o);
    if((t & 63) == 0) red[t >> 6] = v;
  }
  __syncthreads();
  if(t == 0) out[g] = red[0] + red[1] + out_b[0];
}

extern "C" void kernel_launch(void* const* d_in, const int* in_sizes, int n_in,
                              void* d_out, int out_size, void* d_ws, size_t ws_size,
                              hipStream_t stream){
  const float* x     = (const float*)d_in[0];
  const int*   ei    = (const int*)d_in[1];
  const int*   batch = (const int*)d_in[2];
  const float* lin_w = (const float*)d_in[3];
  const float* lin_b = (const float*)d_in[4];
  const float* w1    = (const float*)d_in[5];
  const float* as1   = (const float*)d_in[6];
  const float* ad1   = (const float*)d_in[7];
  const float* b1    = (const float*)d_in[8];
  const float* w2    = (const float*)d_in[9];
  const float* as2   = (const float*)d_in[10];
  const float* ad2   = (const float*)d_in[11];
  const float* b2    = (const float*)d_in[12];
  const float* ow    = (const float*)d_in[13];
  const float* ob    = (const float*)d_in[14];
  float* out = (float*)d_out;

  const int N = in_sizes[0] / 128;
  const int E = in_sizes[1] / 2;
  const int Etot = E + N;
  const int G = out_size;
  const int nbuck = (N + (1 << BSHIFT) - 1) >> BSHIFT;
  const int nsb = (N + 4095) / 4096;     // scan blocks (<=64)

  char* p = (char*)d_ws;
  int*   deg     = (int*)p;   p += (size_t)(N + 1) * 4;
  int*   rowptr  = (int*)p;   p += (size_t)(N + 1) * 4;
  int*   bcur    = (int*)p;   p += (size_t)MAXBUCK * 4;
  int*   bsum    = (int*)p;   p += (size_t)64 * 4;
  int*   gs      = (int*)p;   p += (size_t)G * 4;
  int*   ge      = (int*)p;   p += (size_t)G * 4;
  float* alpha_s = (float*)p; p += (size_t)N * 4;
  float* alpha_d = (float*)p; p += (size_t)N * 4;
  float* Wc      = (float*)p; p += (size_t)128 * 128 * 4;  // Win@W1 composite
  float* bc      = (float*)p; p += (size_t)128 * 4;        // b_in@W1
  int*   esrc    = (int*)p;   p += (size_t)Etot * 4;
  uint2* staged  = (uint2*)p; p += (size_t)Etot * 8;
  unsigned int* hb  = (unsigned int*)p; p += (size_t)N * 64 * 4;  // projection, bf16-packed
  unsigned int* hb2 = (unsigned int*)p; p += (size_t)N * 64 * 4;  // h1 / h2, bf16-packed

  const int ebl = (Etot + 255) / 256;
  k_init<<<(N + 256) / 256, 256, 0, stream>>>(batch, deg, gs, ge, N + 1, N);
  k_hist<<<ebl, 256, 0, stream>>>(ei, deg, E, Etot);
  k_scanA<<<nsb, 1024, 0, stream>>>(deg, rowptr, bsum, N);
  k_scanB<<<1, 64, 0, stream>>>(bsum, nsb);
  k_scanC<<<(N + 255) / 256, 256, 0, stream>>>(rowptr, bsum, bcur, N);
  k_binA<<<(Etot + 4095) / 4096, 256, 0, stream>>>(ei, bcur, staged, E, Etot);
  k_binB<<<nbuck, 256, 0, stream>>>(staged, rowptr, esrc, N);

  // composite: proj1 = x @ (Win@W1) + b_in@W1
  k_prep<<<5, 256, 0, stream>>>(lin_w, lin_b, w1, Wc, bc);

  const int gbl = (N + 63) / 64;
  const int wbl = (N + 3) / 4;

  k_gemm_proj<false><<<gbl, 256, 0, stream>>>(x, Wc, as1, ad1, bc, hb, alpha_s, alpha_d, N);
  k_gat<<<wbl, 256, 0, stream>>>(hb, rowptr, esrc, alpha_s, alpha_d, b1, hb2, N, Etot);
  k_gemm_proj<true><<<gbl, 256, 0, stream>>>(hb2, w2, as2, ad2, nullptr, hb, alpha_s, alpha_d, N);
  k_gat<<<wbl, 256, 0, stream>>>(hb, rowptr, esrc, alpha_s, alpha_d, b2, hb2, N, Etot);
  k_poolout<<<G, 512, 0, stream>>>(hb2, gs, ge, ow, ob, out, N);
}